// Round 1
// baseline (39991.919 us; speedup 1.0000x reference)
//
#include <hip/hip_runtime.h>
#include <hip/hip_cooperative_groups.h>

namespace cg = cooperative_groups;

constexpr int NX = 256, NY = 256;
constexpr int T_STEPS = 256, N_SRC = 3, N_PROBE = 5;
constexpr int RELAX_STEPS = 100;
constexpr int TILE = 16, HALO = 4, LDIM = TILE + 2 * HALO; // 24
constexpr int NBX = NX / TILE, NBY = NY / TILE;            // 16 x 16
constexpr int BLOCKS_PER_SIG = NBX * NBY;                  // 256
constexpr int NSIG = 2;
constexpr int NBLOCKS = BLOCKS_PER_SIG * NSIG;             // 512
constexpr int NTHR = 256;

// h = GAMMA_LL * DT, folded in double then cast (matches JAX weak-typed scalars)
constexpr float H_STEP = (float)(175950000000.0 * 5e-12);          // 0.87975
constexpr float H_HALF = (float)(175950000000.0 * 5e-12 * 0.5);
constexpr float H_6    = (float)(175950000000.0 * 5e-12 / 6.0);
constexpr float C_SOT_F = 1e-4f;

__global__ __launch_bounds__(NTHR, 2)
void mm_kernel(const float* __restrict__ sig,    // [NSIG][T_STEPS][N_SRC]
               const float* __restrict__ Bext,   // [3][NX][NY]
               const float* __restrict__ MsatP,  // scalar
               const int*   __restrict__ srcp,   // [N_SRC][2]
               const int*   __restrict__ prbp,   // [N_PROBE][2]
               const int*   __restrict__ fbP,    // scalar
               float* __restrict__ out,          // [NSIG][T_STEPS][N_PROBE]
               float* __restrict__ F)            // [NSIG][2][3][NX][NY] ping-pong
{
    __shared__ float m_s[3][LDIM][LDIM];
    __shared__ float y_s[3][LDIM][LDIM];
    __shared__ float k_s[3][LDIM][LDIM];
    __shared__ float B_s[3][LDIM][LDIM];

    const int tid = threadIdx.x;
    const int blk = blockIdx.x;
    const int sg  = blk / BLOCKS_PER_SIG;
    const int b   = blk % BLOCKS_PER_SIG;
    const int tbx = b / NBY;
    const int tby = b % NBY;
    const int x0 = tbx * TILE, y0 = tby * TILE;
    const bool atT = (tbx == 0), atB = (tbx == NBX - 1);
    const bool atL = (tby == 0), atR = (tby == NBY - 1);

    const float Msat = MsatP[0];
    // cex = 2*A_EXCH / (Msat*DX*DX), same assoc as reference
    const float cex = (float)(2.0 * 3.5e-12) / (Msat * 5e-8f * 5e-8f);
    const float dmg = (float)(4e-7 * 3.14159265358979323846) * Msat; // MU0*Msat
    const int fb = fbP[0];

    // B tile (clamped load); z-channel of source cells is refreshed per run-step
    for (int idx = tid; idx < LDIM * LDIM; idx += NTHR) {
        const int i = idx / LDIM, j = idx % LDIM;
        const int gx = min(max(x0 - HALO + i, 0), NX - 1);
        const int gy = min(max(y0 - HALO + j, 0), NY - 1);
        B_s[0][i][j] = Bext[0 * NX * NY + gx * NY + gy];
        B_s[1][i][j] = Bext[1 * NX * NY + gx * NY + gy];
        B_s[2][i][j] = Bext[2 * NX * NY + gx * NY + gy];
    }

    const int ti = tid / TILE, tj = tid % TILE;
    const int ii = HALO + ti, jj = HALO + tj;   // my interior cell (LDS coords)
    const int gxi = x0 + ti, gyi = y0 + tj;     // my interior cell (global)

    int probe_idx = -1;
    for (int p = 0; p < N_PROBE; ++p)
        if (prbp[2 * p] == gxi && prbp[2 * p + 1] == gyi) probe_idx = p;

    float* Fsig = F + (size_t)sg * 2 * 3 * NX * NY;

    cg::grid_group grid = cg::this_grid();
    float mrelz = 0.0f;

    const int TOT = RELAX_STEPS + T_STEPS;
    for (int u = 0; u < TOT; ++u) {
        const bool relax = (u < RELAX_STEPS);
        const float alpha = relax ? 0.5f : 0.01f;
        const float pref  = -1.0f / (1.0f + alpha * alpha);
        const int t = u - RELAX_STEPS;

        // ---- Phase A: stage m (with halo) into LDS ----
        if (u == 0) {
            for (int idx = tid; idx < LDIM * LDIM; idx += NTHR) {
                const int i = idx / LDIM, j = idx % LDIM;
                m_s[0][i][j] = 0.0f; m_s[1][i][j] = 1.0f; m_s[2][i][j] = 0.0f;
            }
        } else {
            const float* Fin = Fsig + (size_t)(u & 1) * 3 * NX * NY;
            for (int idx = tid; idx < LDIM * LDIM; idx += NTHR) {
                const int i = idx / LDIM, j = idx % LDIM;
                const int gx = min(max(x0 - HALO + i, 0), NX - 1);
                const int gy = min(max(y0 - HALO + j, 0), NY - 1);
                m_s[0][i][j] = Fin[0 * NX * NY + gx * NY + gy];
                m_s[1][i][j] = Fin[1 * NX * NY + gx * NY + gy];
                m_s[2][i][j] = Fin[2 * NX * NY + gx * NY + gy];
            }
        }
        // source injection (run phase): also needed for halo recompute in neighbors
        if (!relax && tid < N_SRC) {
            const int sx = srcp[2 * tid], sy = srcp[2 * tid + 1];
            const int li = sx - (x0 - HALO), lj = sy - (y0 - HALO);
            if (li >= 0 && li < LDIM && lj >= 0 && lj < LDIM)
                B_s[2][li][lj] = Bext[2 * NX * NY + sx * NY + sy]
                               + sig[((size_t)sg * T_STEPS + t) * N_SRC + tid];
        }
        __syncthreads();

        const float m0r = m_s[0][ii][jj], m1r = m_s[1][ii][jj], m2r = m_s[2][ii][jj];
        float a0 = 0.f, a1 = 0.f, a2 = 0.f;

        // ---- 4 RK4 stages, valid region shrinks by 1/stage on interior sides ----
        for (int s = 1; s <= 4; ++s) {
            float (*f)[LDIM][LDIM] = (s == 1) ? m_s : y_s;
            const int loi = atT ? HALO : s;
            const int hiI = atB ? (HALO + TILE - 1) : (LDIM - 1 - s);
            const int loj = atL ? HALO : s;
            const int hiJ = atR ? (HALO + TILE - 1) : (LDIM - 1 - s);
            const float c = (s <= 2) ? H_HALF : H_STEP;

            for (int idx = tid; idx < LDIM * LDIM; idx += NTHR) {
                const int i = idx / LDIM, j = idx % LDIM;
                if (i < loi || i > hiI || j < loj || j > hiJ) continue;
                const int gx = x0 - HALO + i, gy = y0 - HALO + j;
                // edge-replicate pad applied per stage == clamp reads at domain edge
                const int iu = (gx == 0)      ? i : i - 1;
                const int id = (gx == NX - 1) ? i : i + 1;
                const int jl = (gy == 0)      ? j : j - 1;
                const int jr = (gy == NY - 1) ? j : j + 1;
                const float mx = f[0][i][j], my = f[1][i][j], mz = f[2][i][j];
                // reference order: (x+1) + (x-1) + (y+1) + (y-1) - 4*m
                const float l0 = f[0][id][j] + f[0][iu][j] + f[0][i][jr] + f[0][i][jl] - 4.f * mx;
                const float l1 = f[1][id][j] + f[1][iu][j] + f[1][i][jr] + f[1][i][jl] - 4.f * my;
                const float l2 = f[2][id][j] + f[2][iu][j] + f[2][i][jr] + f[2][i][jl] - 4.f * mz;
                const float B0 = B_s[0][i][j] + cex * l0;
                const float B1 = B_s[1][i][j] + cex * l1;
                const float B2 = B_s[2][i][j] + cex * l2 - dmg * mz;
                // c1 = m x Beff
                const float c10 = my * B2 - mz * B1;
                const float c11 = mz * B0 - mx * B2;
                const float c12 = mx * B1 - my * B0;
                // c2 = m x c1
                const float c20 = my * c12 - mz * c11;
                const float c21 = mz * c10 - mx * c12;
                const float c22 = mx * c11 - my * c10;
                // sot = C_SOT * m x (m x (0,1,0)) = C_SOT*(mx*my, -(mx^2+mz^2), my*mz)
                k_s[0][i][j] = pref * (c10 + alpha * c20) + C_SOT_F * (my * mx);
                k_s[1][i][j] = pref * (c11 + alpha * c21) - C_SOT_F * (mx * mx + mz * mz);
                k_s[2][i][j] = pref * (c12 + alpha * c22) + C_SOT_F * (my * mz);
            }
            __syncthreads();

            // accumulator (registers, my interior cell only)
            {
                const float w = (s == 1 || s == 4) ? 1.f : 2.f;
                a0 += w * k_s[0][ii][jj];
                a1 += w * k_s[1][ii][jj];
                a2 += w * k_s[2][ii][jj];
            }
            // next stage field y = m + c*k over the same region
            if (s < 4) {
                for (int idx = tid; idx < LDIM * LDIM; idx += NTHR) {
                    const int i = idx / LDIM, j = idx % LDIM;
                    if (i < loi || i > hiI || j < loj || j > hiJ) continue;
                    y_s[0][i][j] = m_s[0][i][j] + c * k_s[0][i][j];
                    y_s[1][i][j] = m_s[1][i][j] + c * k_s[1][i][j];
                    y_s[2][i][j] = m_s[2][i][j] + c * k_s[2][i][j];
                }
            }
            __syncthreads();
        }

        // ---- epilogue: m_new, probe output, publish to ping-pong global ----
        const float n0 = m0r + H_6 * a0;
        const float n1 = m1r + H_6 * a1;
        const float n2 = m2r + H_6 * a2;
        float* Fout = Fsig + (size_t)((u + 1) & 1) * 3 * NX * NY;
        Fout[0 * NX * NY + gxi * NY + gyi] = n0;
        Fout[1 * NX * NY + gxi * NY + gyi] = n1;
        Fout[2 * NX * NY + gxi * NY + gyi] = n2;
        if (relax) {
            if (u == RELAX_STEPS - 1 && probe_idx >= 0) mrelz = n2;
        } else if (probe_idx >= 0) {
            out[((size_t)sg * T_STEPS + t) * N_PROBE + probe_idx] =
                fb ? (n2 - mrelz) * Msat : n2;
        }
        __threadfence();
        grid.sync();
    }
}

extern "C" void kernel_launch(void* const* d_in, const int* in_sizes, int n_in,
                              void* d_out, int out_size, void* d_ws, size_t ws_size,
                              hipStream_t stream) {
    const float* sigp  = (const float*)d_in[0];
    const float* Bext  = (const float*)d_in[1];
    const float* Msat  = (const float*)d_in[2];
    const int*   srcp  = (const int*)d_in[3];
    const int*   prbp  = (const int*)d_in[4];
    const int*   fbP   = (const int*)d_in[5];
    float* outp = (float*)d_out;
    float* F    = (float*)d_ws;   // needs NSIG*2*3*NX*NY*4 = 6.29 MB

    void* args[] = { (void*)&sigp, (void*)&Bext, (void*)&Msat, (void*)&srcp,
                     (void*)&prbp, (void*)&fbP, (void*)&outp, (void*)&F };
    hipLaunchCooperativeKernel((void*)mm_kernel, dim3(NBLOCKS), dim3(NTHR),
                               args, 0, stream);
}

// Round 2
// 17206.213 us; speedup vs baseline: 2.3243x; 2.3243x over previous
//
#include <hip/hip_runtime.h>

constexpr int NX = 256, NY = 256;
constexpr int T_STEPS = 256, N_SRC = 3, N_PROBE = 5;
constexpr int RELAX_STEPS = 100;
constexpr int TILE = 16, HALO = 4, LDIM = TILE + 2 * HALO; // 24
constexpr int NBX = NX / TILE, NBY = NY / TILE;            // 16 x 16
constexpr int BPS = NBX * NBY;                             // 256 blocks/signal
constexpr int NSIG = 2;
constexpr int NBLOCKS = BPS * NSIG;                        // 512
constexpr int NTHR = 256;
constexpr int FIELD = 3 * NX * NY;                         // floats per field
constexpr int F_TOTAL = NSIG * 2 * FIELD;                  // ping-pong, both signals
constexpr int FLAG_STRIDE = 16;                            // ints (64 B) per flag

constexpr float H_STEP = (float)(175950000000.0 * 5e-12);
constexpr float H_HALF = (float)(175950000000.0 * 5e-12 * 0.5);
constexpr float H_6    = (float)(175950000000.0 * 5e-12 / 6.0);
constexpr float CSOT   = 1e-4f;

__global__ void init_flags(int* flags) {
    flags[blockIdx.x * blockDim.x + threadIdx.x] = 0;
}

// LLG torque given m and Beff(exch already folded into B0..B2 except demag on B2)
__device__ __forceinline__ void torque(float mx, float my, float mz,
                                       float B0, float B1, float B2,
                                       float pref, float alpha,
                                       float& o0, float& o1, float& o2) {
    const float c10 = my * B2 - mz * B1;
    const float c11 = mz * B0 - mx * B2;
    const float c12 = mx * B1 - my * B0;
    const float c20 = my * c12 - mz * c11;
    const float c21 = mz * c10 - mx * c12;
    const float c22 = mx * c11 - my * c10;
    // sot = C_SOT * m x (m x (0,1,0)) = C_SOT * (mx*my, -(mx^2+mz^2), my*mz)
    o0 = pref * (c10 + alpha * c20) + CSOT * (my * mx);
    o1 = pref * (c11 + alpha * c21) - CSOT * (mx * mx + mz * mz);
    o2 = pref * (c12 + alpha * c22) + CSOT * (my * mz);
}

__global__ __launch_bounds__(NTHR, 2)
void mm_kernel(const float* __restrict__ sig,    // [NSIG][T_STEPS][N_SRC]
               const float* __restrict__ Bext,   // [3][NX][NY]
               const float* __restrict__ MsatP,
               const int*   __restrict__ srcp,   // [N_PROBE? no: N_SRC][2]
               const int*   __restrict__ prbp,   // [N_PROBE][2]
               const int*   __restrict__ fbP,
               float* __restrict__ out,          // [NSIG][T_STEPS][N_PROBE]
               float* __restrict__ F,            // ping-pong fields
               int*   __restrict__ flags)        // [NBLOCKS]*FLAG_STRIDE
{
    // 8 LDS arrays x 3ch x 24x24 x 4B = 55.3 KB -> 2 blocks/CU
    __shared__ float m_s[3][LDIM][LDIM];
    __shared__ float ya[3][LDIM][LDIM];
    __shared__ float yb[3][LDIM][LDIM];
    __shared__ float k1s[3][LDIM][LDIM];
    __shared__ float k2s[3][LDIM][LDIM];
    __shared__ float k3s[3][LDIM][LDIM];
    __shared__ float k4s[3][LDIM][LDIM];
    __shared__ float B_s[3][LDIM][LDIM];

    const int tid = threadIdx.x;
    const int blk = blockIdx.x;
    const int sg  = blk / BPS;
    const int b   = blk % BPS;
    const int tbx = b / NBY, tby = b % NBY;
    const int x0 = tbx * TILE, y0 = tby * TILE;
    const bool atT = (tbx == 0), atB = (tbx == NBX - 1);
    const bool atL = (tby == 0), atR = (tby == NBY - 1);

    const float Msat = MsatP[0];
    const float cex = 7e-12f / (Msat * 5e-8f * 5e-8f);
    const float dmg = (float)(4e-7 * 3.14159265358979323846) * Msat;
    const int fb = fbP[0];
    const float alpha = 0.01f;
    const float pref  = (float)(-(1.0 / (1.0 + 0.01 * 0.01)));

    // neighbor block ids (same signal only)
    int nb[8]; int n_nb = 0;
    for (int dx = -1; dx <= 1; ++dx)
        for (int dy = -1; dy <= 1; ++dy) {
            if (dx == 0 && dy == 0) continue;
            const int nx = tbx + dx, ny = tby + dy;
            if (nx < 0 || nx >= NBX || ny < 0 || ny >= NBY) continue;
            nb[n_nb++] = sg * BPS + nx * NBY + ny;
        }

    // ---- B tile (clamped) ----
    for (int idx = tid; idx < LDIM * LDIM; idx += NTHR) {
        const int i = idx / LDIM, j = idx % LDIM;
        const int gx = min(max(x0 - HALO + i, 0), NX - 1);
        const int gy = min(max(y0 - HALO + j, 0), NY - 1);
        B_s[0][i][j] = Bext[0 * NX * NY + gx * NY + gy];
        B_s[1][i][j] = Bext[1 * NX * NY + gx * NY + gy];
        B_s[2][i][j] = Bext[2 * NX * NY + gx * NY + gy];
    }

    const int ti = tid / TILE, tj = tid % TILE;
    const int ii = HALO + ti, jj = HALO + tj;
    const int gxi = x0 + ti, gyi = y0 + tj;

    int probe_idx = -1;
    for (int p = 0; p < N_PROBE; ++p)
        if (prbp[2 * p] == gxi && prbp[2 * p + 1] == gyi) probe_idx = p;

    // ---- relax phase: spatially uniform => pointwise ODE, exact identity ----
    // (uniform m0, uniform B_ext => Laplacian == 0.0f exactly every step; every
    // cell performs bit-identical arithmetic, so the field stays uniform)
    float r0 = 0.0f, r1 = 1.0f, r2 = 0.0f;
    {
        const float Bx = Bext[0 * NX * NY + gxi * NY + gyi];
        const float By = Bext[1 * NX * NY + gxi * NY + gyi];
        const float Bz = Bext[2 * NX * NY + gxi * NY + gyi];
        const float aR = 0.5f;
        const float pR = (float)(-(1.0 / (1.0 + 0.5 * 0.5)));
        for (int r = 0; r < RELAX_STEPS; ++r) {
            float k10, k11, k12, k20, k21, k22, k30, k31, k32, k40, k41, k42;
            torque(r0, r1, r2, Bx, By, Bz - dmg * r2, pR, aR, k10, k11, k12);
            float u0 = r0 + H_HALF * k10, u1 = r1 + H_HALF * k11, u2 = r2 + H_HALF * k12;
            torque(u0, u1, u2, Bx, By, Bz - dmg * u2, pR, aR, k20, k21, k22);
            u0 = r0 + H_HALF * k20; u1 = r1 + H_HALF * k21; u2 = r2 + H_HALF * k22;
            torque(u0, u1, u2, Bx, By, Bz - dmg * u2, pR, aR, k30, k31, k32);
            u0 = r0 + H_STEP * k30; u1 = r1 + H_STEP * k31; u2 = r2 + H_STEP * k32;
            torque(u0, u1, u2, Bx, By, Bz - dmg * u2, pR, aR, k40, k41, k42);
            r0 += H_6 * (((k10 + 2.0f * k20) + 2.0f * k30) + k40);
            r1 += H_6 * (((k11 + 2.0f * k21) + 2.0f * k31) + k41);
            r2 += H_6 * (((k12 + 2.0f * k22) + 2.0f * k32) + k42);
        }
    }
    const float mrelz = r2;

    // init full LDS tile (interior + halo) to the uniform relaxed state
    for (int idx = tid; idx < LDIM * LDIM; idx += NTHR) {
        const int i = idx / LDIM, j = idx % LDIM;
        m_s[0][i][j] = r0; m_s[1][i][j] = r1; m_s[2][i][j] = r2;
    }
    __syncthreads();

    float* Fsig = F + (size_t)sg * 2 * FIELD;
    int* myflag = flags + blk * FLAG_STRIDE;

    for (int u = 0; u < T_STEPS; ++u) {
        // ---- wait for neighbors to have published state u, then stage halo ----
        if (u > 0) {
            if (tid < n_nb) {
                const int* fp = flags + nb[tid] * FLAG_STRIDE;
                while (__hip_atomic_load(fp, __ATOMIC_ACQUIRE,
                                         __HIP_MEMORY_SCOPE_AGENT) < u)
                    __builtin_amdgcn_s_sleep(1);
            }
            __syncthreads();
            const float* Fin = Fsig + (size_t)(u & 1) * FIELD;
            for (int idx = tid; idx < 320; idx += NTHR) {   // halo ring only
                int i, j;
                if (idx < 96)        { i = idx / 24;              j = idx % 24; }
                else if (idx < 192)  { i = 20 + (idx - 96) / 24;  j = (idx - 96) % 24; }
                else { const int r = idx - 192; i = 4 + r / 8;
                       const int c = r % 8; j = (c < 4) ? c : 12 + c; }
                const int gx = min(max(x0 - HALO + i, 0), NX - 1);
                const int gy = min(max(y0 - HALO + j, 0), NY - 1);
                const int g = gx * NY + gy;
                m_s[0][i][j] = Fin[g];
                m_s[1][i][j] = Fin[NX * NY + g];
                m_s[2][i][j] = Fin[2 * NX * NY + g];
            }
        }
        // source injection into B_s z (also in halo so neighbor recompute sees it)
        if (tid < N_SRC) {
            const int sx = srcp[2 * tid], sy = srcp[2 * tid + 1];
            const int li = sx - (x0 - HALO), lj = sy - (y0 - HALO);
            if (li >= 0 && li < LDIM && lj >= 0 && lj < LDIM)
                B_s[2][li][lj] = Bext[2 * NX * NY + sx * NY + sy]
                               + sig[((size_t)sg * T_STEPS + u) * N_SRC + tid];
        }
        __syncthreads();

        // ---- 4 RK4 stages; fused k-compute + y-update; one sync per stage ----
        for (int s = 1; s <= 4; ++s) {
            const float (*f)[LDIM][LDIM] =
                (s == 1) ? m_s : ((s == 2) ? ya : ((s == 3) ? yb : ya));
            float (*ko)[LDIM][LDIM] =
                (s == 1) ? k1s : ((s == 2) ? k2s : ((s == 3) ? k3s : k4s));
            float (*yo)[LDIM][LDIM] = (s == 1) ? ya : ((s == 2) ? yb : ya);
            const float c = (s <= 2) ? H_HALF : H_STEP;
            const int loi = atT ? HALO : s;
            const int hiI = atB ? (HALO + TILE - 1) : (LDIM - 1 - s);
            const int loj = atL ? HALO : s;
            const int hiJ = atR ? (HALO + TILE - 1) : (LDIM - 1 - s);

            for (int idx = tid; idx < LDIM * LDIM; idx += NTHR) {
                const int i = idx / LDIM, j = idx % LDIM;
                if (i < loi || i > hiI || j < loj || j > hiJ) continue;
                const int gx = x0 - HALO + i, gy = y0 - HALO + j;
                const int iu = (gx == 0)      ? i : i - 1;
                const int id = (gx == NX - 1) ? i : i + 1;
                const int jl = (gy == 0)      ? j : j - 1;
                const int jr = (gy == NY - 1) ? j : j + 1;
                const float mx = f[0][i][j], my = f[1][i][j], mz = f[2][i][j];
                const float l0 = f[0][id][j] + f[0][iu][j] + f[0][i][jr] + f[0][i][jl] - 4.f * mx;
                const float l1 = f[1][id][j] + f[1][iu][j] + f[1][i][jr] + f[1][i][jl] - 4.f * my;
                const float l2 = f[2][id][j] + f[2][iu][j] + f[2][i][jr] + f[2][i][jl] - 4.f * mz;
                float t0, t1, t2;
                torque(mx, my, mz,
                       B_s[0][i][j] + cex * l0,
                       B_s[1][i][j] + cex * l1,
                       B_s[2][i][j] + cex * l2 - dmg * mz,
                       pref, alpha, t0, t1, t2);
                ko[0][i][j] = t0; ko[1][i][j] = t1; ko[2][i][j] = t2;
                if (s < 4) {
                    yo[0][i][j] = m_s[0][i][j] + c * t0;
                    yo[1][i][j] = m_s[1][i][j] + c * t1;
                    yo[2][i][j] = m_s[2][i][j] + c * t2;
                }
            }
            __syncthreads();
        }

        // ---- epilogue: combine, publish, flag ----
        const float n0 = m_s[0][ii][jj] + H_6 * (((k1s[0][ii][jj] + 2.0f * k2s[0][ii][jj]) + 2.0f * k3s[0][ii][jj]) + k4s[0][ii][jj]);
        const float n1 = m_s[1][ii][jj] + H_6 * (((k1s[1][ii][jj] + 2.0f * k2s[1][ii][jj]) + 2.0f * k3s[1][ii][jj]) + k4s[1][ii][jj]);
        const float n2 = m_s[2][ii][jj] + H_6 * (((k1s[2][ii][jj] + 2.0f * k2s[2][ii][jj]) + 2.0f * k3s[2][ii][jj]) + k4s[2][ii][jj]);
        float* Fout = Fsig + (size_t)((u + 1) & 1) * FIELD;
        const int g = gxi * NY + gyi;
        Fout[g] = n0; Fout[NX * NY + g] = n1; Fout[2 * NX * NY + g] = n2;
        // interior stays resident in LDS for the next step
        m_s[0][ii][jj] = n0; m_s[1][ii][jj] = n1; m_s[2][ii][jj] = n2;
        if (probe_idx >= 0)
            out[((size_t)sg * T_STEPS + u) * N_PROBE + probe_idx] =
                fb ? (n2 - mrelz) * Msat : n2;

        __threadfence();      // make tile writes visible at agent scope
        __syncthreads();      // all threads done writing before flag release
        if (tid == 0)
            __hip_atomic_store(myflag, u + 1, __ATOMIC_RELEASE,
                               __HIP_MEMORY_SCOPE_AGENT);
    }
}

extern "C" void kernel_launch(void* const* d_in, const int* in_sizes, int n_in,
                              void* d_out, int out_size, void* d_ws, size_t ws_size,
                              hipStream_t stream) {
    const float* sigp = (const float*)d_in[0];
    const float* Bext = (const float*)d_in[1];
    const float* Msat = (const float*)d_in[2];
    const int*   srcp = (const int*)d_in[3];
    const int*   prbp = (const int*)d_in[4];
    const int*   fbP  = (const int*)d_in[5];
    float* outp = (float*)d_out;
    float* F    = (float*)d_ws;                       // F_TOTAL floats = 3.15 MB
    int*   flags = (int*)((char*)d_ws + (size_t)F_TOTAL * sizeof(float)); // 32 KB

    init_flags<<<NBLOCKS * FLAG_STRIDE / NTHR, NTHR, 0, stream>>>(flags);

    void* args[] = { (void*)&sigp, (void*)&Bext, (void*)&Msat, (void*)&srcp,
                     (void*)&prbp, (void*)&fbP, (void*)&outp, (void*)&F,
                     (void*)&flags };
    hipLaunchCooperativeKernel((void*)mm_kernel, dim3(NBLOCKS), dim3(NTHR),
                               args, 0, stream);
}

// Round 3
// 4169.157 us; speedup vs baseline: 9.5923x; 4.1270x over previous
//
#include <hip/hip_runtime.h>

constexpr int NX = 256, NY = 256;
constexpr int T_STEPS = 256, N_SRC = 3, N_PROBE = 5;
constexpr int RELAX_STEPS = 100;
constexpr int TILE = 16, HALO = 4, LDIM = TILE + 2 * HALO; // 24
constexpr int NBX = NX / TILE, NBY = NY / TILE;            // 16 x 16
constexpr int BPS = NBX * NBY;                             // 256 blocks/signal
constexpr int NSIG = 2;
constexpr int NBLOCKS = BPS * NSIG;                        // 512
constexpr int NTHR = 256;
constexpr int FIELD = 3 * NX * NY;
constexpr int F_TOTAL = NSIG * 2 * FIELD;                  // ping-pong, both signals
constexpr int FLAG_STRIDE = 16;                            // ints (64 B) per flag

constexpr float H_STEP = (float)(175950000000.0 * 5e-12);
constexpr float H_HALF = (float)(175950000000.0 * 5e-12 * 0.5);
constexpr float H_6    = (float)(175950000000.0 * 5e-12 / 6.0);
constexpr float CSOT   = 1e-4f;

__global__ void init_flags(int* flags) {
    flags[blockIdx.x * blockDim.x + threadIdx.x] = 0;
}

__device__ __forceinline__ void torque(float mx, float my, float mz,
                                       float B0, float B1, float B2,
                                       float pref, float alpha,
                                       float& o0, float& o1, float& o2) {
    const float c10 = my * B2 - mz * B1;
    const float c11 = mz * B0 - mx * B2;
    const float c12 = mx * B1 - my * B0;
    const float c20 = my * c12 - mz * c11;
    const float c21 = mz * c10 - mx * c12;
    const float c22 = mx * c11 - my * c10;
    // sot = C_SOT * m x (m x (0,1,0)) = C_SOT * (mx*my, -(mx^2+mz^2), my*mz)
    o0 = pref * (c10 + alpha * c20) + CSOT * (my * mx);
    o1 = pref * (c11 + alpha * c21) - CSOT * (mx * mx + mz * mz);
    o2 = pref * (c12 + alpha * c22) + CSOT * (my * mz);
}

// fine-grained device-coherent accessors (sc0 sc1: straight to coherence point,
// no cache-wide wbl2/inv — the round-2 bottleneck)
__device__ __forceinline__ float cohLoad(const float* p) {
    return __hip_atomic_load(p, __ATOMIC_RELAXED, __HIP_MEMORY_SCOPE_AGENT);
}
__device__ __forceinline__ void cohStore(float* p, float v) {
    __hip_atomic_store(p, v, __ATOMIC_RELAXED, __HIP_MEMORY_SCOPE_AGENT);
}

__global__ __launch_bounds__(NTHR, 2)
void mm_kernel(const float* __restrict__ sig,    // [NSIG][T_STEPS][N_SRC]
               const float* __restrict__ Bext,   // [3][NX][NY]
               const float* __restrict__ MsatP,
               const int*   __restrict__ srcp,   // [N_SRC][2]
               const int*   __restrict__ prbp,   // [N_PROBE][2]
               const int*   __restrict__ fbP,
               float* __restrict__ out,          // [NSIG][T_STEPS][N_PROBE]
               float* __restrict__ F,            // ping-pong fields (ring cells only used)
               int*   __restrict__ flags)        // [NBLOCKS]*FLAG_STRIDE
{
    // 4 x 3x24x24 + acc 3x16x16 = 30.7 KB LDS
    __shared__ float m_s[3][LDIM][LDIM];
    __shared__ float ya[3][LDIM][LDIM];
    __shared__ float yb[3][LDIM][LDIM];
    __shared__ float B_s[3][LDIM][LDIM];
    __shared__ float acc[3][TILE][TILE];

    const int tid = threadIdx.x;
    const int blk = blockIdx.x;
    const int sg  = blk / BPS;
    const int b   = blk % BPS;
    const int tbx = b / NBY, tby = b % NBY;
    const int x0 = tbx * TILE, y0 = tby * TILE;
    const bool atT = (tbx == 0), atB = (tbx == NBX - 1);
    const bool atL = (tby == 0), atR = (tby == NBY - 1);

    const float Msat = MsatP[0];
    const float cex = 7e-12f / (Msat * 5e-8f * 5e-8f);
    const float dmg = (float)(4e-7 * 3.14159265358979323846) * Msat;
    const int fb = fbP[0];
    const float alpha = 0.01f;
    const float pref  = (float)(-(1.0 / (1.0 + 0.01 * 0.01)));

    // neighbor block ids (same signal only)
    int nb[8]; int n_nb = 0;
    for (int dx = -1; dx <= 1; ++dx)
        for (int dy = -1; dy <= 1; ++dy) {
            if (dx == 0 && dy == 0) continue;
            const int nx = tbx + dx, ny = tby + dy;
            if (nx < 0 || nx >= NBX || ny < 0 || ny >= NBY) continue;
            nb[n_nb++] = sg * BPS + nx * NBY + ny;
        }

    for (int idx = tid; idx < LDIM * LDIM; idx += NTHR) {
        const int i = idx / LDIM, j = idx % LDIM;
        const int gx = min(max(x0 - HALO + i, 0), NX - 1);
        const int gy = min(max(y0 - HALO + j, 0), NY - 1);
        B_s[0][i][j] = Bext[0 * NX * NY + gx * NY + gy];
        B_s[1][i][j] = Bext[1 * NX * NY + gx * NY + gy];
        B_s[2][i][j] = Bext[2 * NX * NY + gx * NY + gy];
    }

    const int ti = tid / TILE, tj = tid % TILE;
    const int ii = HALO + ti, jj = HALO + tj;
    const int gxi = x0 + ti, gyi = y0 + tj;
    // ring cell: within 4 of tile edge -> read by some neighbor (or by self-clamp)
    const bool ring = (ti < HALO) || (ti >= TILE - HALO) ||
                      (tj < HALO) || (tj >= TILE - HALO);

    int probe_idx = -1;
    for (int p = 0; p < N_PROBE; ++p)
        if (prbp[2 * p] == gxi && prbp[2 * p + 1] == gyi) probe_idx = p;

    // ---- relax phase: uniform field => Laplacian == 0.0f exactly; pointwise ODE ----
    float r0 = 0.0f, r1 = 1.0f, r2 = 0.0f;
    {
        const float Bx = Bext[0 * NX * NY + gxi * NY + gyi];
        const float By = Bext[1 * NX * NY + gxi * NY + gyi];
        const float Bz = Bext[2 * NX * NY + gxi * NY + gyi];
        const float aR = 0.5f;
        const float pR = (float)(-(1.0 / (1.0 + 0.5 * 0.5)));
        for (int r = 0; r < RELAX_STEPS; ++r) {
            float k10, k11, k12, k20, k21, k22, k30, k31, k32, k40, k41, k42;
            torque(r0, r1, r2, Bx, By, Bz - dmg * r2, pR, aR, k10, k11, k12);
            float u0 = r0 + H_HALF * k10, u1 = r1 + H_HALF * k11, u2 = r2 + H_HALF * k12;
            torque(u0, u1, u2, Bx, By, Bz - dmg * u2, pR, aR, k20, k21, k22);
            u0 = r0 + H_HALF * k20; u1 = r1 + H_HALF * k21; u2 = r2 + H_HALF * k22;
            torque(u0, u1, u2, Bx, By, Bz - dmg * u2, pR, aR, k30, k31, k32);
            u0 = r0 + H_STEP * k30; u1 = r1 + H_STEP * k31; u2 = r2 + H_STEP * k32;
            torque(u0, u1, u2, Bx, By, Bz - dmg * u2, pR, aR, k40, k41, k42);
            r0 += H_6 * (((k10 + 2.0f * k20) + 2.0f * k30) + k40);
            r1 += H_6 * (((k11 + 2.0f * k21) + 2.0f * k31) + k41);
            r2 += H_6 * (((k12 + 2.0f * k22) + 2.0f * k32) + k42);
        }
    }
    const float mrelz = r2;

    for (int idx = tid; idx < LDIM * LDIM; idx += NTHR) {
        const int i = idx / LDIM, j = idx % LDIM;
        m_s[0][i][j] = r0; m_s[1][i][j] = r1; m_s[2][i][j] = r2;
    }
    __syncthreads();

    float* Fsig = F + (size_t)sg * 2 * FIELD;
    int* myflag = flags + blk * FLAG_STRIDE;

    for (int u = 0; u < T_STEPS; ++u) {
        // ---- wait for neighbors (relaxed poll + one acquire confirm) ----
        if (u > 0) {
            if (tid < n_nb) {
                const int* fp = flags + nb[tid] * FLAG_STRIDE;
                while (__hip_atomic_load(fp, __ATOMIC_RELAXED,
                                         __HIP_MEMORY_SCOPE_AGENT) < u)
                    __builtin_amdgcn_s_sleep(2);
                (void)__hip_atomic_load(fp, __ATOMIC_ACQUIRE,
                                        __HIP_MEMORY_SCOPE_AGENT);
            }
            __syncthreads();
            const float* Fin = Fsig + (size_t)(u & 1) * FIELD;
            for (int idx = tid; idx < 320; idx += NTHR) {   // halo ring only
                int i, j;
                if (idx < 96)        { i = idx / 24;              j = idx % 24; }
                else if (idx < 192)  { i = 20 + (idx - 96) / 24;  j = (idx - 96) % 24; }
                else { const int r = idx - 192; i = 4 + r / 8;
                       const int c = r % 8; j = (c < 4) ? c : 12 + c; }
                const int gx = min(max(x0 - HALO + i, 0), NX - 1);
                const int gy = min(max(y0 - HALO + j, 0), NY - 1);
                const int g = gx * NY + gy;
                m_s[0][i][j] = cohLoad(Fin + g);
                m_s[1][i][j] = cohLoad(Fin + NX * NY + g);
                m_s[2][i][j] = cohLoad(Fin + 2 * NX * NY + g);
            }
        }
        // zero the interior RK accumulator
        for (int idx = tid; idx < 3 * TILE * TILE; idx += NTHR)
            ((float*)acc)[idx] = 0.0f;
        // source injection into B_s z (halo too, so neighbor recompute sees it)
        if (tid < N_SRC) {
            const int sx = srcp[2 * tid], sy = srcp[2 * tid + 1];
            const int li = sx - (x0 - HALO), lj = sy - (y0 - HALO);
            if (li >= 0 && li < LDIM && lj >= 0 && lj < LDIM)
                B_s[2][li][lj] = Bext[2 * NX * NY + sx * NY + sy]
                               + sig[((size_t)sg * T_STEPS + u) * N_SRC + tid];
        }
        __syncthreads();

        // ---- 4 RK4 stages; k fused into y-update + interior accumulator ----
        for (int s = 1; s <= 4; ++s) {
            const float (*f)[LDIM][LDIM] =
                (s == 1) ? m_s : ((s == 2) ? ya : ((s == 3) ? yb : ya));
            float (*yo)[LDIM][LDIM] = (s == 2) ? yb : ya;
            const float c = (s <= 2) ? H_HALF : H_STEP;
            const float w = (s == 1 || s == 4) ? 1.0f : 2.0f;
            const int loi = atT ? HALO : s;
            const int hiI = atB ? (HALO + TILE - 1) : (LDIM - 1 - s);
            const int loj = atL ? HALO : s;
            const int hiJ = atR ? (HALO + TILE - 1) : (LDIM - 1 - s);

            for (int idx = tid; idx < LDIM * LDIM; idx += NTHR) {
                const int i = idx / LDIM, j = idx % LDIM;
                if (i < loi || i > hiI || j < loj || j > hiJ) continue;
                const int gx = x0 - HALO + i, gy = y0 - HALO + j;
                const int iu = (gx == 0)      ? i : i - 1;
                const int id = (gx == NX - 1) ? i : i + 1;
                const int jl = (gy == 0)      ? j : j - 1;
                const int jr = (gy == NY - 1) ? j : j + 1;
                const float mx = f[0][i][j], my = f[1][i][j], mz = f[2][i][j];
                const float l0 = f[0][id][j] + f[0][iu][j] + f[0][i][jr] + f[0][i][jl] - 4.f * mx;
                const float l1 = f[1][id][j] + f[1][iu][j] + f[1][i][jr] + f[1][i][jl] - 4.f * my;
                const float l2 = f[2][id][j] + f[2][iu][j] + f[2][i][jr] + f[2][i][jl] - 4.f * mz;
                float t0, t1, t2;
                torque(mx, my, mz,
                       B_s[0][i][j] + cex * l0,
                       B_s[1][i][j] + cex * l1,
                       B_s[2][i][j] + cex * l2 - dmg * mz,
                       pref, alpha, t0, t1, t2);
                if (s < 4) {
                    yo[0][i][j] = m_s[0][i][j] + c * t0;
                    yo[1][i][j] = m_s[1][i][j] + c * t1;
                    yo[2][i][j] = m_s[2][i][j] + c * t2;
                }
                if (i >= HALO && i < HALO + TILE && j >= HALO && j < HALO + TILE) {
                    // one writer per cell; order = ((k1+2k2)+2k3)+k4, same as ref
                    acc[0][i - HALO][j - HALO] += w * t0;
                    acc[1][i - HALO][j - HALO] += w * t1;
                    acc[2][i - HALO][j - HALO] += w * t2;
                }
            }
            __syncthreads();
        }

        // ---- epilogue: combine, keep interior in LDS, publish ring, flag ----
        const float n0 = m_s[0][ii][jj] + H_6 * acc[0][ti][tj];
        const float n1 = m_s[1][ii][jj] + H_6 * acc[1][ti][tj];
        const float n2 = m_s[2][ii][jj] + H_6 * acc[2][ti][tj];
        m_s[0][ii][jj] = n0; m_s[1][ii][jj] = n1; m_s[2][ii][jj] = n2;
        if (probe_idx >= 0)
            out[((size_t)sg * T_STEPS + u) * N_PROBE + probe_idx] =
                fb ? (n2 - mrelz) * Msat : n2;

        if (u + 1 < T_STEPS) {
            if (ring) {
                float* Fout = Fsig + (size_t)((u + 1) & 1) * FIELD;
                const int g = gxi * NY + gyi;
                cohStore(Fout + g, n0);
                cohStore(Fout + NX * NY + g, n1);
                cohStore(Fout + 2 * NX * NY + g, n2);
            }
            __builtin_amdgcn_s_waitcnt(0);   // own coherent stores ack'd at LLC
            __syncthreads();                  // all threads' stores drained
            if (tid == 0)
                __hip_atomic_store(myflag, u + 1, __ATOMIC_RELEASE,
                                   __HIP_MEMORY_SCOPE_AGENT);
        } else {
            __syncthreads();
        }
    }
}

extern "C" void kernel_launch(void* const* d_in, const int* in_sizes, int n_in,
                              void* d_out, int out_size, void* d_ws, size_t ws_size,
                              hipStream_t stream) {
    const float* sigp = (const float*)d_in[0];
    const float* Bext = (const float*)d_in[1];
    const float* Msat = (const float*)d_in[2];
    const int*   srcp = (const int*)d_in[3];
    const int*   prbp = (const int*)d_in[4];
    const int*   fbP  = (const int*)d_in[5];
    float* outp = (float*)d_out;
    float* F    = (float*)d_ws;                       // 3.15 MB
    int*   flags = (int*)((char*)d_ws + (size_t)F_TOTAL * sizeof(float)); // 32 KB

    init_flags<<<NBLOCKS * FLAG_STRIDE / NTHR, NTHR, 0, stream>>>(flags);

    void* args[] = { (void*)&sigp, (void*)&Bext, (void*)&Msat, (void*)&srcp,
                     (void*)&prbp, (void*)&fbP, (void*)&outp, (void*)&F,
                     (void*)&flags };
    hipLaunchCooperativeKernel((void*)mm_kernel, dim3(NBLOCKS), dim3(NTHR),
                               args, 0, stream);
}

// Round 4
// 2225.059 us; speedup vs baseline: 17.9734x; 1.8737x over previous
//
#include <hip/hip_runtime.h>

constexpr int NX = 256, NY = 256;
constexpr int T_STEPS = 256, N_SRC = 3, N_PROBE = 5;
constexpr int RELAX_STEPS = 100;
constexpr int TILE = 16, HALO = 8, LDIM = TILE + 2 * HALO; // 32
constexpr int NBX = NX / TILE, NBY = NY / TILE;            // 16 x 16
constexpr int BPS = NBX * NBY;                             // 256 blocks/signal
constexpr int NSIG = 2;
constexpr int NBLOCKS = BPS * NSIG;                        // 512
constexpr int NTHR = 256;
constexpr int NPAIR = T_STEPS / 2;                         // 128 exchanges
constexpr int FIELD = 3 * NX * NY;
constexpr int F_TOTAL = NSIG * 2 * FIELD;
constexpr int FLAG_STRIDE = 16;

constexpr float H_STEP = (float)(175950000000.0 * 5e-12);
constexpr float H_HALF = (float)(175950000000.0 * 5e-12 * 0.5);
constexpr float H_6    = (float)(175950000000.0 * 5e-12 / 6.0);
constexpr float CSOT   = 1e-4f;

__global__ void init_flags(int* flags) {
    flags[blockIdx.x * blockDim.x + threadIdx.x] = 0;
}

__device__ __forceinline__ void torque(float mx, float my, float mz,
                                       float B0, float B1, float B2,
                                       float pref, float alpha,
                                       float& o0, float& o1, float& o2) {
    const float c10 = my * B2 - mz * B1;
    const float c11 = mz * B0 - mx * B2;
    const float c12 = mx * B1 - my * B0;
    const float c20 = my * c12 - mz * c11;
    const float c21 = mz * c10 - mx * c12;
    const float c22 = mx * c11 - my * c10;
    // sot = C_SOT * m x (m x (0,1,0)) = C_SOT*(mx*my, -(mx^2+mz^2), my*mz)
    o0 = pref * (c10 + alpha * c20) + CSOT * (my * mx);
    o1 = pref * (c11 + alpha * c21) - CSOT * (mx * mx + mz * mz);
    o2 = pref * (c12 + alpha * c22) + CSOT * (my * mz);
}

// fine-grained device-coherent accessors: sc0 sc1 read/write at the coherence
// point. NO release/acquire anywhere in the steady state -> no buffer_wbl2 /
// buffer_inv cache-wide ops (the round-3 residual bottleneck).
__device__ __forceinline__ float cohLoad(const float* p) {
    return __hip_atomic_load(p, __ATOMIC_RELAXED, __HIP_MEMORY_SCOPE_AGENT);
}
__device__ __forceinline__ void cohStore(float* p, float v) {
    __hip_atomic_store(p, v, __ATOMIC_RELAXED, __HIP_MEMORY_SCOPE_AGENT);
}

__global__ __launch_bounds__(NTHR, 2)
void mm_kernel(const float* __restrict__ sig,    // [NSIG][T_STEPS][N_SRC]
               const float* __restrict__ Bext,   // [3][NX][NY]
               const float* __restrict__ MsatP,
               const int*   __restrict__ srcp,   // [N_SRC][2]
               const int*   __restrict__ prbp,   // [N_PROBE][2]
               const int*   __restrict__ fbP,
               float* __restrict__ out,          // [NSIG][T_STEPS][N_PROBE]
               float* __restrict__ F,            // ping-pong ring buffers
               int*   __restrict__ flags)
{
    // 5 x 3x32x32 x 4B = 61.4 KB -> 2 blocks/CU
    __shared__ float m_s[3][LDIM][LDIM];
    __shared__ float ya [3][LDIM][LDIM];
    __shared__ float yb [3][LDIM][LDIM];
    __shared__ float B_s[3][LDIM][LDIM];
    __shared__ float acc[3][LDIM][LDIM];

    const int tid = threadIdx.x;
    const int blk = blockIdx.x;
    const int sg  = blk / BPS;
    const int b   = blk % BPS;
    const int tbx = b / NBY, tby = b % NBY;
    const int x0 = tbx * TILE, y0 = tby * TILE;
    const bool atT = (tbx == 0), atB = (tbx == NBX - 1);
    const bool atL = (tby == 0), atR = (tby == NBY - 1);

    const float Msat = MsatP[0];
    const float cex = 7e-12f / (Msat * 5e-8f * 5e-8f);
    const float dmg = (float)(4e-7 * 3.14159265358979323846) * Msat;
    const int fb = fbP[0];
    const float alpha = 0.01f;
    const float pref  = (float)(-(1.0 / (1.0 + 0.01 * 0.01)));

    int nb[8]; int n_nb = 0;
    for (int dx = -1; dx <= 1; ++dx)
        for (int dy = -1; dy <= 1; ++dy) {
            if (dx == 0 && dy == 0) continue;
            const int nx = tbx + dx, ny = tby + dy;
            if (nx < 0 || nx >= NBX || ny < 0 || ny >= NBY) continue;
            nb[n_nb++] = sg * BPS + nx * NBY + ny;
        }

    // B tile (clamped) + acc zero
    for (int idx = tid; idx < LDIM * LDIM; idx += NTHR) {
        const int i = idx / LDIM, j = idx % LDIM;
        const int gx = min(max(x0 - HALO + i, 0), NX - 1);
        const int gy = min(max(y0 - HALO + j, 0), NY - 1);
        B_s[0][i][j] = Bext[0 * NX * NY + gx * NY + gy];
        B_s[1][i][j] = Bext[1 * NX * NY + gx * NY + gy];
        B_s[2][i][j] = Bext[2 * NX * NY + gx * NY + gy];
        acc[0][i][j] = 0.0f; acc[1][i][j] = 0.0f; acc[2][i][j] = 0.0f;
    }

    const int ti = tid / TILE, tj = tid % TILE;
    const int ii = HALO + ti, jj = HALO + tj;
    const int gxi = x0 + ti, gyi = y0 + tj;

    int probe_idx = -1;
    for (int p = 0; p < N_PROBE; ++p)
        if (prbp[2 * p] == gxi && prbp[2 * p + 1] == gyi) probe_idx = p;

    // ---- relax: uniform field => Laplacian == 0.0f exactly; pointwise ODE ----
    float r0 = 0.0f, r1 = 1.0f, r2 = 0.0f;
    {
        const float Bx = Bext[0 * NX * NY + gxi * NY + gyi];
        const float By = Bext[1 * NX * NY + gxi * NY + gyi];
        const float Bz = Bext[2 * NX * NY + gxi * NY + gyi];
        const float aR = 0.5f;
        const float pR = (float)(-(1.0 / (1.0 + 0.5 * 0.5)));
        for (int r = 0; r < RELAX_STEPS; ++r) {
            float k10,k11,k12,k20,k21,k22,k30,k31,k32,k40,k41,k42;
            torque(r0,r1,r2, Bx,By,Bz - dmg*r2, pR,aR, k10,k11,k12);
            float u0=r0+H_HALF*k10, u1=r1+H_HALF*k11, u2=r2+H_HALF*k12;
            torque(u0,u1,u2, Bx,By,Bz - dmg*u2, pR,aR, k20,k21,k22);
            u0=r0+H_HALF*k20; u1=r1+H_HALF*k21; u2=r2+H_HALF*k22;
            torque(u0,u1,u2, Bx,By,Bz - dmg*u2, pR,aR, k30,k31,k32);
            u0=r0+H_STEP*k30; u1=r1+H_STEP*k31; u2=r2+H_STEP*k32;
            torque(u0,u1,u2, Bx,By,Bz - dmg*u2, pR,aR, k40,k41,k42);
            r0 += H_6 * (((k10 + 2.0f*k20) + 2.0f*k30) + k40);
            r1 += H_6 * (((k11 + 2.0f*k21) + 2.0f*k31) + k41);
            r2 += H_6 * (((k12 + 2.0f*k22) + 2.0f*k32) + k42);
        }
    }
    const float mrelz = r2;

    for (int idx = tid; idx < LDIM * LDIM; idx += NTHR) {
        const int i = idx / LDIM, j = idx % LDIM;
        m_s[0][i][j] = r0; m_s[1][i][j] = r1; m_s[2][i][j] = r2;
    }

    float* Fsig = F + (size_t)sg * 2 * FIELD;
    int* myflag = flags + blk * FLAG_STRIDE;

    for (int pr = 0; pr < NPAIR; ++pr) {
        // ---- handshake: poll neighbors (relaxed), stage 768-cell halo ----
        if (pr > 0) {
            if (tid < n_nb) {
                const int* fp = flags + nb[tid] * FLAG_STRIDE;
                while (__hip_atomic_load(fp, __ATOMIC_RELAXED,
                                         __HIP_MEMORY_SCOPE_AGENT) < pr)
                    __builtin_amdgcn_s_sleep(1);
            }
            __syncthreads();
            const float* Fin = Fsig + (size_t)(pr & 1) * FIELD;
            for (int idx = tid; idx < 768; idx += NTHR) {
                int i, j;
                if (idx < 256)      { i = idx >> 5;               j = idx & 31; }
                else if (idx < 512) { i = 24 + ((idx - 256) >> 5); j = idx & 31; }
                else { const int r = idx - 512; i = 8 + (r >> 4);
                       const int c = r & 15; j = (c < 8) ? c : 16 + c; }
                const int gx = min(max(x0 - HALO + i, 0), NX - 1);
                const int gy = min(max(y0 - HALO + j, 0), NY - 1);
                const int g = gx * NY + gy;
                m_s[0][i][j] = cohLoad(Fin + g);
                m_s[1][i][j] = cohLoad(Fin + NX * NY + g);
                m_s[2][i][j] = cohLoad(Fin + 2 * NX * NY + g);
            }
        }
        // source injection for step u = 2*pr
        if (tid < N_SRC) {
            const int sx = srcp[2 * tid], sy = srcp[2 * tid + 1];
            const int li = sx - (x0 - HALO), lj = sy - (y0 - HALO);
            if (li >= 0 && li < LDIM && lj >= 0 && lj < LDIM)
                B_s[2][li][lj] = Bext[2 * NX * NY + sx * NY + sy]
                               + sig[((size_t)sg * T_STEPS + 2 * pr) * N_SRC + tid];
        }
        __syncthreads();

        for (int p = 0; p < 2; ++p) {
            const int bsh = 4 * p;
            // bounds of this step's final (shrink bsh+4) region
            const int loA  = atT ? HALO : bsh + 4;
            const int hiA  = atB ? (HALO + TILE - 1) : (LDIM - 1 - (bsh + 4));
            const int loAj = atL ? HALO : bsh + 4;
            const int hiAj = atR ? (HALO + TILE - 1) : (LDIM - 1 - (bsh + 4));

            for (int s = 1; s <= 4; ++s) {
                const float (*f)[LDIM][LDIM] =
                    (s == 1) ? m_s : ((s == 2) ? ya : ((s == 3) ? yb : ya));
                float (*yo)[LDIM][LDIM] = (s == 2) ? yb : ya;
                const float c = (s <= 2) ? H_HALF : H_STEP;
                const float w = (s == 1 || s == 4) ? 1.0f : 2.0f;
                const int sh = bsh + s;
                const int loi = atT ? HALO : sh;
                const int hiI = atB ? (HALO + TILE - 1) : (LDIM - 1 - sh);
                const int loj = atL ? HALO : sh;
                const int hiJ = atR ? (HALO + TILE - 1) : (LDIM - 1 - sh);
                const int W = hiJ - loj + 1, Hh = hiI - loi + 1;

                for (int idx = tid; idx < W * Hh; idx += NTHR) {
                    const int i = loi + idx / W, j = loj + idx % W;
                    const int gx = x0 - HALO + i, gy = y0 - HALO + j;
                    const int iu = (gx == 0)      ? i : i - 1;
                    const int id = (gx == NX - 1) ? i : i + 1;
                    const int jl = (gy == 0)      ? j : j - 1;
                    const int jr = (gy == NY - 1) ? j : j + 1;
                    const float mx = f[0][i][j], my = f[1][i][j], mz = f[2][i][j];
                    const float l0 = f[0][id][j] + f[0][iu][j] + f[0][i][jr] + f[0][i][jl] - 4.f * mx;
                    const float l1 = f[1][id][j] + f[1][iu][j] + f[1][i][jr] + f[1][i][jl] - 4.f * my;
                    const float l2 = f[2][id][j] + f[2][iu][j] + f[2][i][jr] + f[2][i][jl] - 4.f * mz;
                    float t0, t1, t2;
                    torque(mx, my, mz,
                           B_s[0][i][j] + cex * l0,
                           B_s[1][i][j] + cex * l1,
                           B_s[2][i][j] + cex * l2 - dmg * mz,
                           pref, alpha, t0, t1, t2);
                    if (s < 4) {
                        yo[0][i][j] = m_s[0][i][j] + c * t0;
                        yo[1][i][j] = m_s[1][i][j] + c * t1;
                        yo[2][i][j] = m_s[2][i][j] + c * t2;
                    }
                    if (i >= loA && i <= hiA && j >= loAj && j <= hiAj) {
                        // order over stages = ((k1+2k2)+2k3)+k4, same as ref
                        acc[0][i][j] += w * t0;
                        acc[1][i][j] += w * t1;
                        acc[2][i][j] += w * t2;
                    }
                }
                __syncthreads();
            }

            // ---- step update: own interior cell in registers ----
            const float n0 = m_s[0][ii][jj] + H_6 * acc[0][ii][jj];
            const float n1 = m_s[1][ii][jj] + H_6 * acc[1][ii][jj];
            const float n2 = m_s[2][ii][jj] + H_6 * acc[2][ii][jj];
            m_s[0][ii][jj] = n0; m_s[1][ii][jj] = n1; m_s[2][ii][jj] = n2;
            acc[0][ii][jj] = 0.f; acc[1][ii][jj] = 0.f; acc[2][ii][jj] = 0.f;
            if (probe_idx >= 0)
                out[((size_t)sg * T_STEPS + 2 * pr + p) * N_PROBE + probe_idx] =
                    fb ? (n2 - mrelz) * Msat : n2;

            if (p == 0) {
                // update the 320-cell ring of the shrink-4 region (non-interior)
                for (int idx = tid; idx < 320; idx += NTHR) {
                    int i, j;
                    if (idx < 96)        { i = 4 + idx / 24;          j = 4 + idx % 24; }
                    else if (idx < 192)  { i = 24 + (idx - 96) / 24;  j = 4 + (idx - 96) % 24; }
                    else { const int r = idx - 192; i = 8 + r / 8;
                           const int c = r % 8; j = (c < 4) ? 4 + c : 20 + c; }
                    if (i < loA || i > hiA || j < loAj || j > hiAj) continue;
                    m_s[0][i][j] += H_6 * acc[0][i][j]; acc[0][i][j] = 0.f;
                    m_s[1][i][j] += H_6 * acc[1][i][j]; acc[1][i][j] = 0.f;
                    m_s[2][i][j] += H_6 * acc[2][i][j]; acc[2][i][j] = 0.f;
                }
                // source injection for step u = 2*pr+1
                if (tid < N_SRC) {
                    const int sx = srcp[2 * tid], sy = srcp[2 * tid + 1];
                    const int li = sx - (x0 - HALO), lj = sy - (y0 - HALO);
                    if (li >= 0 && li < LDIM && lj >= 0 && lj < LDIM)
                        B_s[2][li][lj] = Bext[2 * NX * NY + sx * NY + sy]
                                       + sig[((size_t)sg * T_STEPS + 2 * pr + 1) * N_SRC + tid];
                }
                __syncthreads();
            } else if (pr + 1 < NPAIR) {
                // ---- publish whole tile (all cells are some neighbor's halo) ----
                float* Fout = Fsig + (size_t)((pr + 1) & 1) * FIELD;
                const int g = gxi * NY + gyi;
                cohStore(Fout + g, n0);
                cohStore(Fout + NX * NY + g, n1);
                cohStore(Fout + 2 * NX * NY + g, n2);
                __builtin_amdgcn_s_waitcnt(0);   // stores ack'd at coherence point
                __syncthreads();                  // whole block drained
                if (tid == 0)
                    __hip_atomic_store(myflag, pr + 1, __ATOMIC_RELAXED,
                                       __HIP_MEMORY_SCOPE_AGENT);
            }
        }
    }
}

extern "C" void kernel_launch(void* const* d_in, const int* in_sizes, int n_in,
                              void* d_out, int out_size, void* d_ws, size_t ws_size,
                              hipStream_t stream) {
    const float* sigp = (const float*)d_in[0];
    const float* Bext = (const float*)d_in[1];
    const float* Msat = (const float*)d_in[2];
    const int*   srcp = (const int*)d_in[3];
    const int*   prbp = (const int*)d_in[4];
    const int*   fbP  = (const int*)d_in[5];
    float* outp = (float*)d_out;
    float* F    = (float*)d_ws;                       // 3.15 MB
    int*   flags = (int*)((char*)d_ws + (size_t)F_TOTAL * sizeof(float)); // 32 KB

    init_flags<<<NBLOCKS * FLAG_STRIDE / NTHR, NTHR, 0, stream>>>(flags);

    void* args[] = { (void*)&sigp, (void*)&Bext, (void*)&Msat, (void*)&srcp,
                     (void*)&prbp, (void*)&fbP, (void*)&outp, (void*)&F,
                     (void*)&flags };
    hipLaunchCooperativeKernel((void*)mm_kernel, dim3(NBLOCKS), dim3(NTHR),
                               args, 0, stream);
}

// Round 5
// 1939.240 us; speedup vs baseline: 20.6225x; 1.1474x over previous
//
#include <hip/hip_runtime.h>

constexpr int NX = 256, NY = 256;
constexpr int T_STEPS = 256, N_SRC = 3, N_PROBE = 5;
constexpr int RELAX_STEPS = 100;
constexpr int TILE = 16, HALO = 8, LDIM = 32, LDIMP = 33; // +1 pad: kill pow2 bank stride
constexpr int NBX = NX / TILE, NBY = NY / TILE;           // 16 x 16
constexpr int BPS = NBX * NBY;                            // 256 blocks/signal
constexpr int NSIG = 2;
constexpr int NBLOCKS = BPS * NSIG;                       // 512
constexpr int NTHR = 512;
constexpr int NPAIR = T_STEPS / 2;                        // 128 exchanges
constexpr int FIELD = 3 * NX * NY;
constexpr int F_TOTAL = NSIG * 2 * FIELD;
constexpr int FLAG_STRIDE = 16;

constexpr float H_STEP = (float)(175950000000.0 * 5e-12);
constexpr float H_HALF = (float)(175950000000.0 * 5e-12 * 0.5);
constexpr float H_6    = (float)(175950000000.0 * 5e-12 / 6.0);
constexpr float CSOT   = 1e-4f;

__global__ void init_flags(int* flags) {
    flags[blockIdx.x * blockDim.x + threadIdx.x] = 0;
}

__device__ __forceinline__ void torque(float mx, float my, float mz,
                                       float B0, float B1, float B2,
                                       float pref, float alpha,
                                       float& o0, float& o1, float& o2) {
    const float c10 = my * B2 - mz * B1;
    const float c11 = mz * B0 - mx * B2;
    const float c12 = mx * B1 - my * B0;
    const float c20 = my * c12 - mz * c11;
    const float c21 = mz * c10 - mx * c12;
    const float c22 = mx * c11 - my * c10;
    // sot = C_SOT * m x (m x (0,1,0)) = C_SOT*(mx*my, -(mx^2+mz^2), my*mz)
    o0 = pref * (c10 + alpha * c20) + CSOT * (my * mx);
    o1 = pref * (c11 + alpha * c21) - CSOT * (mx * mx + mz * mz);
    o2 = pref * (c12 + alpha * c22) + CSOT * (my * mz);
}

// fine-grained device-coherent accessors (sc0 sc1; no wbl2/inv cache-wide ops)
__device__ __forceinline__ float cohLoad(const float* p) {
    return __hip_atomic_load(p, __ATOMIC_RELAXED, __HIP_MEMORY_SCOPE_AGENT);
}
__device__ __forceinline__ void cohStore(float* p, float v) {
    __hip_atomic_store(p, v, __ATOMIC_RELAXED, __HIP_MEMORY_SCOPE_AGENT);
}

// One RK4 stage over the rectangle [loi..hiI]x[loj..hiJ].
// EDGE=false: interior block, no per-cell boundary clamps (252 of 256 blocks).
template<bool EDGE>
__device__ __forceinline__ void run_stage(
    const float (*f)[LDIM][LDIMP],  float (*yo)[LDIM][LDIMP],
    const float (*m)[LDIM][LDIMP],  float (*accp)[LDIM][LDIMP],
    const float (*B)[LDIM][LDIMP],
    int tid, int x0, int y0,
    int loi, int hiI, int loj, int hiJ,
    int loA, int hiA, int loAj, int hiAj,
    float c, float w, bool doY,
    float cex, float dmg, float pref, float alpha)
{
    const int W = hiJ - loj + 1;
    const int Hh = hiI - loi + 1;
    for (int idx = tid; idx < W * Hh; idx += NTHR) {
        const int i = loi + idx / W, j = loj + idx % W;
        int iu = i - 1, id = i + 1, jl = j - 1, jr = j + 1;
        if (EDGE) {
            const int gx = x0 - HALO + i, gy = y0 - HALO + j;
            if (gx == 0)      iu = i;
            if (gx == NX - 1) id = i;
            if (gy == 0)      jl = j;
            if (gy == NY - 1) jr = j;
        }
        const float mx = f[0][i][j], my = f[1][i][j], mz = f[2][i][j];
        const float l0 = f[0][id][j] + f[0][iu][j] + f[0][i][jr] + f[0][i][jl] - 4.f * mx;
        const float l1 = f[1][id][j] + f[1][iu][j] + f[1][i][jr] + f[1][i][jl] - 4.f * my;
        const float l2 = f[2][id][j] + f[2][iu][j] + f[2][i][jr] + f[2][i][jl] - 4.f * mz;
        float t0, t1, t2;
        torque(mx, my, mz,
               B[0][i][j] + cex * l0,
               B[1][i][j] + cex * l1,
               B[2][i][j] + cex * l2 - dmg * mz,
               pref, alpha, t0, t1, t2);
        if (doY) {
            yo[0][i][j] = m[0][i][j] + c * t0;
            yo[1][i][j] = m[1][i][j] + c * t1;
            yo[2][i][j] = m[2][i][j] + c * t2;
        }
        if (i >= loA && i <= hiA && j >= loAj && j <= hiAj) {
            // one writer per cell; order over stages = ((k1+2k2)+2k3)+k4, as ref
            accp[0][i][j] += w * t0;
            accp[1][i][j] += w * t1;
            accp[2][i][j] += w * t2;
        }
    }
}

__global__ __launch_bounds__(NTHR, 4)
void mm_kernel(const float* __restrict__ sig,    // [NSIG][T_STEPS][N_SRC]
               const float* __restrict__ Bext,   // [3][NX][NY]
               const float* __restrict__ MsatP,
               const int*   __restrict__ srcp,   // [N_SRC][2]
               const int*   __restrict__ prbp,   // [N_PROBE][2]
               const int*   __restrict__ fbP,
               float* __restrict__ out,          // [NSIG][T_STEPS][N_PROBE]
               float* __restrict__ F,            // ping-pong ring buffers
               int*   __restrict__ flags)
{
    // 5 x 3x32x33 x 4B = 63.4 KB -> 2 blocks/CU (126.7 <= 160 KB)
    __shared__ float m_s[3][LDIM][LDIMP];
    __shared__ float ya [3][LDIM][LDIMP];
    __shared__ float yb [3][LDIM][LDIMP];
    __shared__ float B_s[3][LDIM][LDIMP];
    __shared__ float acc[3][LDIM][LDIMP];

    const int tid = threadIdx.x;
    const int blk = blockIdx.x;
    const int sg  = blk / BPS;
    const int b   = blk % BPS;
    const int tbx = b / NBY, tby = b % NBY;
    const int x0 = tbx * TILE, y0 = tby * TILE;
    const bool atT = (tbx == 0), atB = (tbx == NBX - 1);
    const bool atL = (tby == 0), atR = (tby == NBY - 1);
    const bool edge = atT || atB || atL || atR;

    const float Msat = MsatP[0];
    const float cex = 7e-12f / (Msat * 5e-8f * 5e-8f);
    const float dmg = (float)(4e-7 * 3.14159265358979323846) * Msat;
    const int fb = fbP[0];
    const float alpha = 0.01f;
    const float pref  = (float)(-(1.0 / (1.0 + 0.01 * 0.01)));

    int nb[8]; int n_nb = 0;
    for (int dx = -1; dx <= 1; ++dx)
        for (int dy = -1; dy <= 1; ++dy) {
            if (dx == 0 && dy == 0) continue;
            const int nx = tbx + dx, ny = tby + dy;
            if (nx < 0 || nx >= NBX || ny < 0 || ny >= NBY) continue;
            nb[n_nb++] = sg * BPS + nx * NBY + ny;
        }

    // B tile (clamped) + acc zero
    for (int idx = tid; idx < LDIM * LDIM; idx += NTHR) {
        const int i = idx / LDIM, j = idx % LDIM;
        const int gx = min(max(x0 - HALO + i, 0), NX - 1);
        const int gy = min(max(y0 - HALO + j, 0), NY - 1);
        B_s[0][i][j] = Bext[0 * NX * NY + gx * NY + gy];
        B_s[1][i][j] = Bext[1 * NX * NY + gx * NY + gy];
        B_s[2][i][j] = Bext[2 * NX * NY + gx * NY + gy];
        acc[0][i][j] = 0.0f; acc[1][i][j] = 0.0f; acc[2][i][j] = 0.0f;
    }

    const bool owner = (tid < TILE * TILE);
    const int ti = tid / TILE, tj = tid % TILE;           // valid for owners
    const int ii = HALO + ti, jj = HALO + tj;
    const int gxi = x0 + ti, gyi = y0 + tj;
    const int gxc = min(gxi, NX - 1), gyc = min(gyi, NY - 1); // clamped for non-owners

    int probe_idx = -1;
    if (owner)
        for (int p = 0; p < N_PROBE; ++p)
            if (prbp[2 * p] == gxi && prbp[2 * p + 1] == gyi) probe_idx = p;

    // ---- relax: uniform field => Laplacian == 0.0f exactly; pointwise ODE ----
    float r0 = 0.0f, r1 = 1.0f, r2 = 0.0f;
    {
        const float Bx = Bext[0 * NX * NY + gxc * NY + gyc];
        const float By = Bext[1 * NX * NY + gxc * NY + gyc];
        const float Bz = Bext[2 * NX * NY + gxc * NY + gyc];
        const float aR = 0.5f;
        const float pR = (float)(-(1.0 / (1.0 + 0.5 * 0.5)));
        for (int r = 0; r < RELAX_STEPS; ++r) {
            float k10,k11,k12,k20,k21,k22,k30,k31,k32,k40,k41,k42;
            torque(r0,r1,r2, Bx,By,Bz - dmg*r2, pR,aR, k10,k11,k12);
            float u0=r0+H_HALF*k10, u1=r1+H_HALF*k11, u2=r2+H_HALF*k12;
            torque(u0,u1,u2, Bx,By,Bz - dmg*u2, pR,aR, k20,k21,k22);
            u0=r0+H_HALF*k20; u1=r1+H_HALF*k21; u2=r2+H_HALF*k22;
            torque(u0,u1,u2, Bx,By,Bz - dmg*u2, pR,aR, k30,k31,k32);
            u0=r0+H_STEP*k30; u1=r1+H_STEP*k31; u2=r2+H_STEP*k32;
            torque(u0,u1,u2, Bx,By,Bz - dmg*u2, pR,aR, k40,k41,k42);
            r0 += H_6 * (((k10 + 2.0f*k20) + 2.0f*k30) + k40);
            r1 += H_6 * (((k11 + 2.0f*k21) + 2.0f*k31) + k41);
            r2 += H_6 * (((k12 + 2.0f*k22) + 2.0f*k32) + k42);
        }
    }
    const float mrelz = r2;

    for (int idx = tid; idx < LDIM * LDIM; idx += NTHR) {
        const int i = idx / LDIM, j = idx % LDIM;
        m_s[0][i][j] = r0; m_s[1][i][j] = r1; m_s[2][i][j] = r2;
    }

    float* Fsig = F + (size_t)sg * 2 * FIELD;
    int* myflag = flags + blk * FLAG_STRIDE;

    for (int pr = 0; pr < NPAIR; ++pr) {
        // ---- handshake: poll neighbors (relaxed), stage 768-cell halo ----
        if (pr > 0) {
            if (tid < n_nb) {
                const int* fp = flags + nb[tid] * FLAG_STRIDE;
                while (__hip_atomic_load(fp, __ATOMIC_RELAXED,
                                         __HIP_MEMORY_SCOPE_AGENT) < pr)
                    __builtin_amdgcn_s_sleep(1);
            }
            __syncthreads();
            const float* Fin = Fsig + (size_t)(pr & 1) * FIELD;
            for (int idx = tid; idx < 768; idx += NTHR) {
                int i, j;
                if (idx < 256)      { i = idx >> 5;                j = idx & 31; }
                else if (idx < 512) { i = 24 + ((idx - 256) >> 5); j = idx & 31; }
                else { const int r = idx - 512; i = 8 + (r >> 4);
                       const int c = r & 15; j = (c < 8) ? c : 16 + c; }
                const int gx = min(max(x0 - HALO + i, 0), NX - 1);
                const int gy = min(max(y0 - HALO + j, 0), NY - 1);
                const int g = gx * NY + gy;
                m_s[0][i][j] = cohLoad(Fin + g);
                m_s[1][i][j] = cohLoad(Fin + NX * NY + g);
                m_s[2][i][j] = cohLoad(Fin + 2 * NX * NY + g);
            }
        }
        // source injection for step u = 2*pr
        if (tid < N_SRC) {
            const int sx = srcp[2 * tid], sy = srcp[2 * tid + 1];
            const int li = sx - (x0 - HALO), lj = sy - (y0 - HALO);
            if (li >= 0 && li < LDIM && lj >= 0 && lj < LDIM)
                B_s[2][li][lj] = Bext[2 * NX * NY + sx * NY + sy]
                               + sig[((size_t)sg * T_STEPS + 2 * pr) * N_SRC + tid];
        }
        __syncthreads();

        for (int p = 0; p < 2; ++p) {
            const int bsh = 4 * p;
            const int loA  = atT ? HALO : bsh + 4;
            const int hiA  = atB ? (HALO + TILE - 1) : (LDIM - 1 - (bsh + 4));
            const int loAj = atL ? HALO : bsh + 4;
            const int hiAj = atR ? (HALO + TILE - 1) : (LDIM - 1 - (bsh + 4));

            for (int s = 1; s <= 4; ++s) {
                const float (*f)[LDIM][LDIMP] =
                    (s == 1) ? m_s : ((s == 2) ? ya : ((s == 3) ? yb : ya));
                float (*yo)[LDIM][LDIMP] = (s == 2) ? yb : ya;
                const float c = (s <= 2) ? H_HALF : H_STEP;
                const float w = (s == 1 || s == 4) ? 1.0f : 2.0f;
                const int sh = bsh + s;
                const int loi = atT ? HALO : sh;
                const int hiI = atB ? (HALO + TILE - 1) : (LDIM - 1 - sh);
                const int loj = atL ? HALO : sh;
                const int hiJ = atR ? (HALO + TILE - 1) : (LDIM - 1 - sh);

                if (edge)
                    run_stage<true >(f, yo, m_s, acc, B_s, tid, x0, y0,
                                     loi, hiI, loj, hiJ, loA, hiA, loAj, hiAj,
                                     c, w, s < 4, cex, dmg, pref, alpha);
                else
                    run_stage<false>(f, yo, m_s, acc, B_s, tid, x0, y0,
                                     loi, hiI, loj, hiJ, loA, hiA, loAj, hiAj,
                                     c, w, s < 4, cex, dmg, pref, alpha);
                __syncthreads();
            }

            // ---- step update: own interior cell ----
            float n0 = 0.f, n1 = 0.f, n2 = 0.f;
            if (owner) {
                n0 = m_s[0][ii][jj] + H_6 * acc[0][ii][jj];
                n1 = m_s[1][ii][jj] + H_6 * acc[1][ii][jj];
                n2 = m_s[2][ii][jj] + H_6 * acc[2][ii][jj];
                m_s[0][ii][jj] = n0; m_s[1][ii][jj] = n1; m_s[2][ii][jj] = n2;
                acc[0][ii][jj] = 0.f; acc[1][ii][jj] = 0.f; acc[2][ii][jj] = 0.f;
                if (probe_idx >= 0)
                    out[((size_t)sg * T_STEPS + 2 * pr + p) * N_PROBE + probe_idx] =
                        fb ? (n2 - mrelz) * Msat : n2;
            }

            if (p == 0) {
                // update the 320-cell ring of the shrink-4 region (non-interior)
                for (int idx = tid; idx < 320; idx += NTHR) {
                    int i, j;
                    if (idx < 96)        { i = 4 + idx / 24;          j = 4 + idx % 24; }
                    else if (idx < 192)  { i = 24 + (idx - 96) / 24;  j = 4 + (idx - 96) % 24; }
                    else { const int r = idx - 192; i = 8 + r / 8;
                           const int c = r % 8; j = (c < 4) ? 4 + c : 20 + c; }
                    if (i < loA || i > hiA || j < loAj || j > hiAj) continue;
                    m_s[0][i][j] += H_6 * acc[0][i][j]; acc[0][i][j] = 0.f;
                    m_s[1][i][j] += H_6 * acc[1][i][j]; acc[1][i][j] = 0.f;
                    m_s[2][i][j] += H_6 * acc[2][i][j]; acc[2][i][j] = 0.f;
                }
                // source injection for step u = 2*pr+1
                if (tid < N_SRC) {
                    const int sx = srcp[2 * tid], sy = srcp[2 * tid + 1];
                    const int li = sx - (x0 - HALO), lj = sy - (y0 - HALO);
                    if (li >= 0 && li < LDIM && lj >= 0 && lj < LDIM)
                        B_s[2][li][lj] = Bext[2 * NX * NY + sx * NY + sy]
                                       + sig[((size_t)sg * T_STEPS + 2 * pr + 1) * N_SRC + tid];
                }
                __syncthreads();
            } else if (pr + 1 < NPAIR) {
                // ---- publish whole tile, drain, flag (all relaxed) ----
                if (owner) {
                    float* Fout = Fsig + (size_t)((pr + 1) & 1) * FIELD;
                    const int g = gxi * NY + gyi;
                    cohStore(Fout + g, n0);
                    cohStore(Fout + NX * NY + g, n1);
                    cohStore(Fout + 2 * NX * NY + g, n2);
                }
                __builtin_amdgcn_s_waitcnt(0);   // stores ack'd at coherence point
                __syncthreads();                  // whole block drained
                if (tid == 0)
                    __hip_atomic_store(myflag, pr + 1, __ATOMIC_RELAXED,
                                       __HIP_MEMORY_SCOPE_AGENT);
            }
        }
    }
}

extern "C" void kernel_launch(void* const* d_in, const int* in_sizes, int n_in,
                              void* d_out, int out_size, void* d_ws, size_t ws_size,
                              hipStream_t stream) {
    const float* sigp = (const float*)d_in[0];
    const float* Bext = (const float*)d_in[1];
    const float* Msat = (const float*)d_in[2];
    const int*   srcp = (const int*)d_in[3];
    const int*   prbp = (const int*)d_in[4];
    const int*   fbP  = (const int*)d_in[5];
    float* outp = (float*)d_out;
    float* F    = (float*)d_ws;                       // 3.15 MB
    int*   flags = (int*)((char*)d_ws + (size_t)F_TOTAL * sizeof(float)); // 32 KB

    init_flags<<<NBLOCKS * FLAG_STRIDE / 256, 256, 0, stream>>>(flags);

    void* args[] = { (void*)&sigp, (void*)&Bext, (void*)&Msat, (void*)&srcp,
                     (void*)&prbp, (void*)&fbP, (void*)&outp, (void*)&F,
                     (void*)&flags };
    hipLaunchCooperativeKernel((void*)mm_kernel, dim3(NBLOCKS), dim3(NTHR),
                               args, 0, stream);
}

// Round 6
// 1643.025 us; speedup vs baseline: 24.3404x; 1.1803x over previous
//
#include <hip/hip_runtime.h>

constexpr int NX = 256, NY = 256;
constexpr int T_STEPS = 256, N_SRC = 3, N_PROBE = 5;
constexpr int RELAX_STEPS = 100;
constexpr int TILE = 16, HALO = 8, LDIM = 32, LPITCH = 34; // even pitch: float2 rows stay 8B-aligned
constexpr int NBX = NX / TILE, NBY = NY / TILE;            // 16 x 16
constexpr int BPS = NBX * NBY;                             // 256 blocks/signal
constexpr int NSIG = 2;
constexpr int NBLOCKS = BPS * NSIG;                        // 512
constexpr int NTHR = 512;                                  // 1 thread : 2 j-adjacent cells
constexpr int NPAIR = T_STEPS / 2;                         // 128 exchanges
constexpr int FIELD = 3 * NX * NY;
constexpr int F_TOTAL = NSIG * 2 * FIELD;
constexpr int FLAG_STRIDE = 16;

constexpr float H_STEP = (float)(175950000000.0 * 5e-12);
constexpr float H_HALF = (float)(175950000000.0 * 5e-12 * 0.5);
constexpr float H_6    = (float)(175950000000.0 * 5e-12 / 6.0);
constexpr float CSOT   = 1e-4f;

__global__ void init_flags(int* flags) {
    flags[blockIdx.x * blockDim.x + threadIdx.x] = 0;
}

__device__ __forceinline__ void torque(float mx, float my, float mz,
                                       float B0, float B1, float B2,
                                       float pref, float alpha,
                                       float& o0, float& o1, float& o2) {
    const float c10 = my * B2 - mz * B1;
    const float c11 = mz * B0 - mx * B2;
    const float c12 = mx * B1 - my * B0;
    const float c20 = my * c12 - mz * c11;
    const float c21 = mz * c10 - mx * c12;
    const float c22 = mx * c11 - my * c10;
    // sot = C_SOT * m x (m x (0,1,0)) = C_SOT*(mx*my, -(mx^2+mz^2), my*mz)
    o0 = pref * (c10 + alpha * c20) + CSOT * (my * mx);
    o1 = pref * (c11 + alpha * c21) - CSOT * (mx * mx + mz * mz);
    o2 = pref * (c12 + alpha * c22) + CSOT * (my * mz);
}

// relax phase: spatially uniform field => Laplacian == 0.0f exactly every step;
// pointwise ODE, bit-identical to the reference's full-grid RK4.
__device__ __forceinline__ void relax_ode(float Bx, float By, float Bz, float dmg,
                                          float& r0, float& r1, float& r2) {
    r0 = 0.0f; r1 = 1.0f; r2 = 0.0f;
    const float aR = 0.5f;
    const float pR = (float)(-(1.0 / (1.0 + 0.5 * 0.5)));
    for (int it = 0; it < RELAX_STEPS; ++it) {
        float k10,k11,k12,k20,k21,k22,k30,k31,k32,k40,k41,k42;
        torque(r0,r1,r2, Bx,By,Bz - dmg*r2, pR,aR, k10,k11,k12);
        float u0=r0+H_HALF*k10, u1=r1+H_HALF*k11, u2=r2+H_HALF*k12;
        torque(u0,u1,u2, Bx,By,Bz - dmg*u2, pR,aR, k20,k21,k22);
        u0=r0+H_HALF*k20; u1=r1+H_HALF*k21; u2=r2+H_HALF*k22;
        torque(u0,u1,u2, Bx,By,Bz - dmg*u2, pR,aR, k30,k31,k32);
        u0=r0+H_STEP*k30; u1=r1+H_STEP*k31; u2=r2+H_STEP*k32;
        torque(u0,u1,u2, Bx,By,Bz - dmg*u2, pR,aR, k40,k41,k42);
        r0 += H_6 * (((k10 + 2.0f*k20) + 2.0f*k30) + k40);
        r1 += H_6 * (((k11 + 2.0f*k21) + 2.0f*k31) + k41);
        r2 += H_6 * (((k12 + 2.0f*k22) + 2.0f*k32) + k42);
    }
}

// fine-grained device-coherent accessors (sc0 sc1; no cache-wide wbl2/inv)
__device__ __forceinline__ float cohLoad(const float* p) {
    return __hip_atomic_load(p, __ATOMIC_RELAXED, __HIP_MEMORY_SCOPE_AGENT);
}
__device__ __forceinline__ void cohStore(float* p, float v) {
    __hip_atomic_store(p, v, __ATOMIC_RELAXED, __HIP_MEMORY_SCOPE_AGENT);
}

__global__ __launch_bounds__(NTHR, 4)
void mm_kernel(const float* __restrict__ sig,    // [NSIG][T_STEPS][N_SRC]
               const float* __restrict__ Bext,   // [3][NX][NY]
               const float* __restrict__ MsatP,
               const int*   __restrict__ srcp,   // [N_SRC][2]
               const int*   __restrict__ prbp,   // [N_PROBE][2]
               const int*   __restrict__ fbP,
               float* __restrict__ out,          // [NSIG][T_STEPS][N_PROBE]
               float* __restrict__ F,            // ping-pong exchange buffers
               int*   __restrict__ flags)
{
    // only 2 exchange buffers in LDS: 2 x 3 x 32 x 34 x 4B = 26.1 KB
    __shared__ float bufA[3][LDIM][LPITCH];
    __shared__ float bufB[3][LDIM][LPITCH];

    const int tid = threadIdx.x;
    const int blk = blockIdx.x;
    const int sg  = blk / BPS;
    const int b   = blk % BPS;
    const int tbx = b / NBY, tby = b % NBY;
    const int x0 = tbx * TILE, y0 = tby * TILE;
    const bool atT = (tbx == 0), atB = (tbx == NBX - 1);
    const bool atL = (tby == 0), atR = (tby == NBY - 1);

    const float Msat = MsatP[0];
    const float cex = 7e-12f / (Msat * 5e-8f * 5e-8f);
    const float dmg = (float)(4e-7 * 3.14159265358979323846) * Msat;
    const int fb = fbP[0];
    const float alpha = 0.01f;
    const float pref  = (float)(-(1.0 / (1.0 + 0.01 * 0.01)));

    // fixed cell ownership: thread -> row r, cols (c2, c2+1)
    const int r  = tid >> 4;
    const int c2 = (tid & 15) << 1;
    const int gx  = x0 - HALO + r;
    const int gy0 = y0 - HALO + c2;
    const int gy1 = gy0 + 1;
    const int gxc  = min(max(gx, 0), NX - 1);
    const int gyc0 = min(max(gy0, 0), NY - 1);
    const int gyc1 = min(max(gy1, 0), NY - 1);
    // domain-edge clamps (cell1 can't be at gy==0, cell0 can't be at gy==255: parity)
    const bool cUp = (gxc == 0), cDn = (gxc == NX - 1);
    const bool cL  = (gyc0 == 0), cR  = (gyc1 == NY - 1);
    const bool interior = (r >= HALO && r < HALO + TILE &&
                           c2 >= HALO && c2 < HALO + TILE); // pair-uniform (c2 even)

    // per-cell source / probe ids (match on clamped coords: halo copies of a
    // source cell must see the same injected B as the owner)
    int sid0 = -1, sid1 = -1, pid0 = -1, pid1 = -1;
    for (int k = 0; k < N_SRC; ++k) {
        if (srcp[2*k] == gxc && srcp[2*k+1] == gyc0) sid0 = k;
        if (srcp[2*k] == gxc && srcp[2*k+1] == gyc1) sid1 = k;
    }
    if (interior)
        for (int k = 0; k < N_PROBE; ++k) {
            if (prbp[2*k] == gx && prbp[2*k+1] == gy0) pid0 = k;
            if (prbp[2*k] == gx && prbp[2*k+1] == gy1) pid1 = k;
        }

    // per-cell B in registers (no LDS for B)
    const float bx0 = Bext[0*NX*NY + gxc*NY + gyc0];
    const float bx1 = Bext[0*NX*NY + gxc*NY + gyc1];
    const float by0 = Bext[1*NX*NY + gxc*NY + gyc0];
    const float by1 = Bext[1*NX*NY + gxc*NY + gyc1];
    const float bz0 = Bext[2*NX*NY + gxc*NY + gyc0];
    const float bz1 = Bext[2*NX*NY + gxc*NY + gyc1];

    // relax (uniform -> exact pointwise identity), per cell
    float m00,m01,m02, m10,m11,m12;
    relax_ode(bx0,by0,bz0,dmg, m00,m01,m02);
    relax_ode(bx1,by1,bz1,dmg, m10,m11,m12);
    const float mrelz0 = m02, mrelz1 = m12;

    // RK accumulators + current-stage own values, all registers
    float a00=0.f,a01=0.f,a02=0.f, a10=0.f,a11=0.f,a12=0.f;
    float f00,f01,f02, f10,f11,f12;

    float* Fsig = F + (size_t)sg * 2 * FIELD;
    int* myflag = flags + blk * FLAG_STRIDE;

    for (int pr = 0; pr < NPAIR; ++pr) {
        // ---- handshake: poll 8 neighbors (relaxed), reload halo cells ----
        if (pr > 0) {
            if (tid < 8) {
                const int k = (tid < 4) ? tid : tid + 1;   // skip (0,0)
                const int nx = tbx + k / 3 - 1, ny = tby + k % 3 - 1;
                if (nx >= 0 && nx < NBX && ny >= 0 && ny < NBY) {
                    const int* fp = flags + (sg * BPS + nx * NBY + ny) * FLAG_STRIDE;
                    while (__hip_atomic_load(fp, __ATOMIC_RELAXED,
                                             __HIP_MEMORY_SCOPE_AGENT) < pr)
                        __builtin_amdgcn_s_sleep(1);
                }
            }
            __syncthreads();
            if (!interior) {
                const float* Fin = Fsig + (size_t)(pr & 1) * FIELD;
                const int g0 = gxc * NY + gyc0, g1 = gxc * NY + gyc1;
                m00 = cohLoad(Fin + g0);              m10 = cohLoad(Fin + g1);
                m01 = cohLoad(Fin + NX*NY + g0);      m11 = cohLoad(Fin + NX*NY + g1);
                m02 = cohLoad(Fin + 2*NX*NY + g0);    m12 = cohLoad(Fin + 2*NX*NY + g1);
            }
        }
        // stage m into bufA; f = m
        *(float2*)&bufA[0][r][c2] = float2{m00, m10};
        *(float2*)&bufA[1][r][c2] = float2{m01, m11};
        *(float2*)&bufA[2][r][c2] = float2{m02, m12};
        f00=m00; f01=m01; f02=m02; f10=m10; f11=m11; f12=m12;
        __syncthreads();

        for (int p = 0; p < 2; ++p) {
            const int tt = 2 * pr + p;
            float b2c0 = bz0, b2c1 = bz1;
            if (sid0 >= 0) b2c0 = bz0 + sig[((size_t)sg*T_STEPS + tt)*N_SRC + sid0];
            if (sid1 >= 0) b2c1 = bz1 + sig[((size_t)sg*T_STEPS + tt)*N_SRC + sid1];

            // accumulation/update region for this step (shrink 4p+4, edge-extended)
            const int rl  = atT ? HALO : 4*p + 4;
            const int rh  = atB ? HALO + TILE - 1 : 27 - 4*p;
            const int clo = atL ? HALO : 4*p + 4;
            const int chi = atR ? HALO + TILE - 1 : 27 - 4*p;
            const bool in0 = (r >= rl && r <= rh && c2   >= clo && c2   <= chi);
            const bool in1 = (r >= rl && r <= rh && c2+1 >= clo && c2+1 <= chi);

            for (int s = 1; s <= 4; ++s) {
                const int sh = 4*p + s;
                const int loi = atT ? HALO : sh;
                const int hiI = atB ? HALO + TILE - 1 : LDIM - 1 - sh;
                const int loj = atL ? HALO : sh;
                const int hiJ = atR ? HALO + TILE - 1 : LDIM - 1 - sh;
                const float cc = (s <= 2) ? H_HALF : H_STEP;
                const float w  = (s == 1 || s == 4) ? 1.0f : 2.0f;
                const float (*P)[LDIM][LPITCH] = (sh & 1) ? bufA : bufB;
                float (*Q)[LDIM][LPITCH] = (sh & 1) ? bufB : bufA;

                if (r >= loi && r <= hiI && c2 + 1 >= loj && c2 <= hiJ) {
                    const float fo0[3] = {f00, f01, f02};
                    const float fo1[3] = {f10, f11, f12};
                    float l0[3], l1[3];
                    #pragma unroll
                    for (int ch = 0; ch < 3; ++ch) {
                        float upx, upy, dnx, dny;
                        if (cUp) { upx = fo0[ch]; upy = fo1[ch]; }
                        else { const float2 u = *(const float2*)&P[ch][r-1][c2]; upx = u.x; upy = u.y; }
                        if (cDn) { dnx = fo0[ch]; dny = fo1[ch]; }
                        else { const float2 d = *(const float2*)&P[ch][r+1][c2]; dnx = d.x; dny = d.y; }
                        const float lf = cL ? fo0[ch] : P[ch][r][c2-1];
                        const float rt = cR ? fo1[ch] : P[ch][r][c2+2];
                        // reference order: (x+1) + (x-1) + (y+1) + (y-1) - 4*m
                        l0[ch] = dnx + upx + fo1[ch] + lf - 4.f * fo0[ch];
                        l1[ch] = dny + upy + rt + fo0[ch] - 4.f * fo1[ch];
                    }
                    float tq00,tq01,tq02, tq10,tq11,tq12;
                    torque(f00,f01,f02,
                           bx0 + cex*l0[0], by0 + cex*l0[1], b2c0 + cex*l0[2] - dmg*f02,
                           pref, alpha, tq00,tq01,tq02);
                    torque(f10,f11,f12,
                           bx1 + cex*l1[0], by1 + cex*l1[1], b2c1 + cex*l1[2] - dmg*f12,
                           pref, alpha, tq10,tq11,tq12);
                    if (in0) { a00 += w*tq00; a01 += w*tq01; a02 += w*tq02; }
                    if (in1) { a10 += w*tq10; a11 += w*tq11; a12 += w*tq12; }
                    if (s < 4) {
                        f00 = m00 + cc*tq00; f01 = m01 + cc*tq01; f02 = m02 + cc*tq02;
                        f10 = m10 + cc*tq10; f11 = m11 + cc*tq11; f12 = m12 + cc*tq12;
                        *(float2*)&Q[0][r][c2] = float2{f00, f10};
                        *(float2*)&Q[1][r][c2] = float2{f01, f11};
                        *(float2*)&Q[2][r][c2] = float2{f02, f12};
                    }
                }
                if (s < 4) __syncthreads();
            }

            // ---- step update (registers; order ((k1+2k2)+2k3)+k4 preserved) ----
            if (in0) { m00 += H_6*a00; m01 += H_6*a01; m02 += H_6*a02; a00=a01=a02=0.f; }
            if (in1) { m10 += H_6*a10; m11 += H_6*a11; m12 += H_6*a12; a10=a11=a12=0.f; }
            f00=m00; f01=m01; f02=m02; f10=m10; f11=m11; f12=m12;
            if (pid0 >= 0)
                out[((size_t)sg*T_STEPS + tt)*N_PROBE + pid0] = fb ? (m02 - mrelz0)*Msat : m02;
            if (pid1 >= 0)
                out[((size_t)sg*T_STEPS + tt)*N_PROBE + pid1] = fb ? (m12 - mrelz1)*Msat : m12;

            if (p == 0) {
                // re-stage updated m for the second half-step (s5 reads bufA)
                *(float2*)&bufA[0][r][c2] = float2{m00, m10};
                *(float2*)&bufA[1][r][c2] = float2{m01, m11};
                *(float2*)&bufA[2][r][c2] = float2{m02, m12};
                __syncthreads();
            } else if (pr + 1 < NPAIR) {
                // ---- publish interior tile, drain, flag (all relaxed) ----
                if (interior) {
                    float* Fout = Fsig + (size_t)((pr + 1) & 1) * FIELD;
                    const int g0 = gx * NY + gy0;
                    cohStore(Fout + g0,             m00);
                    cohStore(Fout + g0 + 1,         m10);
                    cohStore(Fout + NX*NY + g0,     m01);
                    cohStore(Fout + NX*NY + g0 + 1, m11);
                    cohStore(Fout + 2*NX*NY + g0,     m02);
                    cohStore(Fout + 2*NX*NY + g0 + 1, m12);
                }
                __builtin_amdgcn_s_waitcnt(0);   // own stores ack'd at coherence point
                __syncthreads();                  // whole block drained
                if (tid == 0)
                    __hip_atomic_store(myflag, pr + 1, __ATOMIC_RELAXED,
                                       __HIP_MEMORY_SCOPE_AGENT);
            }
        }
    }
}

extern "C" void kernel_launch(void* const* d_in, const int* in_sizes, int n_in,
                              void* d_out, int out_size, void* d_ws, size_t ws_size,
                              hipStream_t stream) {
    const float* sigp = (const float*)d_in[0];
    const float* Bext = (const float*)d_in[1];
    const float* Msat = (const float*)d_in[2];
    const int*   srcp = (const int*)d_in[3];
    const int*   prbp = (const int*)d_in[4];
    const int*   fbP  = (const int*)d_in[5];
    float* outp = (float*)d_out;
    float* F    = (float*)d_ws;                       // 3.15 MB
    int*   flags = (int*)((char*)d_ws + (size_t)F_TOTAL * sizeof(float)); // 32 KB

    init_flags<<<NBLOCKS * FLAG_STRIDE / 256, 256, 0, stream>>>(flags);

    void* args[] = { (void*)&sigp, (void*)&Bext, (void*)&Msat, (void*)&srcp,
                     (void*)&prbp, (void*)&fbP, (void*)&outp, (void*)&F,
                     (void*)&flags };
    hipLaunchCooperativeKernel((void*)mm_kernel, dim3(NBLOCKS), dim3(NTHR),
                               args, 0, stream);
}

// Round 7
// 1232.492 us; speedup vs baseline: 32.4480x; 1.3331x over previous
//
#include <hip/hip_runtime.h>

constexpr int NX = 256, NY = 256;
constexpr int T_STEPS = 256, N_SRC = 3, N_PROBE = 5;
constexpr int RELAX_STEPS = 100;
constexpr int TILE = 16, HALO = 8, LDIM = 32, LPAIR = 17; // 17 f2-pairs = 34 floats pitch
constexpr int NBX = NX / TILE, NBY = NY / TILE;           // 16 x 16
constexpr int BPS = NBX * NBY;                            // 256 blocks/signal
constexpr int NSIG = 2;
constexpr int NBLOCKS = BPS * NSIG;                       // 512
constexpr int NTHR = 512;                                 // 1 thread : 2 j-adjacent cells
constexpr int NPAIR = T_STEPS / 2;                        // 128 exchanges
constexpr int FIELD = 3 * NX * NY;
constexpr int F_TOTAL = NSIG * 2 * FIELD;
constexpr int FLAG_STRIDE = 16;

constexpr float H_STEP = (float)(175950000000.0 * 5e-12);
constexpr float H_HALF = (float)(175950000000.0 * 5e-12 * 0.5);
constexpr float H_6    = (float)(175950000000.0 * 5e-12 / 6.0);
constexpr float CSOT   = 1e-4f;

typedef float f2 __attribute__((ext_vector_type(2)));

__global__ void init_flags(int* flags) {
    flags[blockIdx.x * blockDim.x + threadIdx.x] = 0;
}

// Packed (2-cell) LLG torque. Per-lane expression trees are token-identical to
// the scalar version benched in rounds 2-6 (absmax 0): v_pk_fma == v_fma per lane.
__device__ __forceinline__ void torque2(f2 mx, f2 my, f2 mz,
                                        f2 B0, f2 B1, f2 B2,
                                        float pref, float alpha,
                                        f2& o0, f2& o1, f2& o2) {
    const f2 c10 = my * B2 - mz * B1;
    const f2 c11 = mz * B0 - mx * B2;
    const f2 c12 = mx * B1 - my * B0;
    const f2 c20 = my * c12 - mz * c11;
    const f2 c21 = mz * c10 - mx * c12;
    const f2 c22 = mx * c11 - my * c10;
    // sot = C_SOT * m x (m x (0,1,0)) = C_SOT*(mx*my, -(mx^2+mz^2), my*mz)
    o0 = pref * (c10 + alpha * c20) + CSOT * (my * mx);
    o1 = pref * (c11 + alpha * c21) - CSOT * (mx * mx + mz * mz);
    o2 = pref * (c12 + alpha * c22) + CSOT * (my * mz);
}

// relax phase: spatially uniform field => Laplacian == 0.0f exactly every step;
// pointwise ODE, bit-identical to the reference's full-grid RK4.
__device__ __forceinline__ void relax_ode2(f2 Bx, f2 By, f2 Bz, float dmg,
                                           f2& r0, f2& r1, f2& r2) {
    r0 = 0.0f; r1 = 1.0f; r2 = 0.0f;
    const float aR = 0.5f;
    const float pR = (float)(-(1.0 / (1.0 + 0.5 * 0.5)));
    for (int it = 0; it < RELAX_STEPS; ++it) {
        f2 k10,k11,k12,k20,k21,k22,k30,k31,k32,k40,k41,k42;
        torque2(r0,r1,r2, Bx,By,Bz - dmg*r2, pR,aR, k10,k11,k12);
        f2 u0=r0+H_HALF*k10, u1=r1+H_HALF*k11, u2=r2+H_HALF*k12;
        torque2(u0,u1,u2, Bx,By,Bz - dmg*u2, pR,aR, k20,k21,k22);
        u0=r0+H_HALF*k20; u1=r1+H_HALF*k21; u2=r2+H_HALF*k22;
        torque2(u0,u1,u2, Bx,By,Bz - dmg*u2, pR,aR, k30,k31,k32);
        u0=r0+H_STEP*k30; u1=r1+H_STEP*k31; u2=r2+H_STEP*k32;
        torque2(u0,u1,u2, Bx,By,Bz - dmg*u2, pR,aR, k40,k41,k42);
        r0 += H_6 * (((k10 + 2.0f*k20) + 2.0f*k30) + k40);
        r1 += H_6 * (((k11 + 2.0f*k21) + 2.0f*k31) + k41);
        r2 += H_6 * (((k12 + 2.0f*k22) + 2.0f*k32) + k42);
    }
}

// fine-grained device-coherent accessors (sc0 sc1; no cache-wide wbl2/inv)
__device__ __forceinline__ float cohLoad(const float* p) {
    return __hip_atomic_load(p, __ATOMIC_RELAXED, __HIP_MEMORY_SCOPE_AGENT);
}
__device__ __forceinline__ void cohStore(float* p, float v) {
    __hip_atomic_store(p, v, __ATOMIC_RELAXED, __HIP_MEMORY_SCOPE_AGENT);
}

__global__ __launch_bounds__(NTHR, 4)
void mm_kernel(const float* __restrict__ sig,    // [NSIG][T_STEPS][N_SRC]
               const float* __restrict__ Bext,   // [3][NX][NY]
               const float* __restrict__ MsatP,
               const int*   __restrict__ srcp,   // [N_SRC][2]
               const int*   __restrict__ prbp,   // [N_PROBE][2]
               const int*   __restrict__ fbP,
               float* __restrict__ out,          // [NSIG][T_STEPS][N_PROBE]
               float* __restrict__ F,            // ping-pong exchange buffers
               int*   __restrict__ flags)
{
    // 2 exchange buffers: 2 x 3 x 32 x 17 x 8B = 26.1 KB
    __shared__ f2 bufA[3][LDIM][LPAIR];
    __shared__ f2 bufB[3][LDIM][LPAIR];

    const int tid = threadIdx.x;
    const int blk = blockIdx.x;
    const int sg  = blk / BPS;
    const int b   = blk % BPS;
    const int tbx = b / NBY, tby = b % NBY;
    const int x0 = tbx * TILE, y0 = tby * TILE;
    const bool atT = (tbx == 0), atB = (tbx == NBX - 1);
    const bool atL = (tby == 0), atR = (tby == NBY - 1);

    const float Msat = MsatP[0];
    const float cex = 7e-12f / (Msat * 5e-8f * 5e-8f);
    const float dmg = (float)(4e-7 * 3.14159265358979323846) * Msat;
    const int fb = fbP[0];
    const float alpha = 0.01f;
    const float pref  = (float)(-(1.0 / (1.0 + 0.01 * 0.01)));

    // fixed cell ownership: thread -> row r, pair pp (cols c2, c2+1)
    const int r  = tid >> 4;
    const int pp = tid & 15;
    const int c2 = pp << 1;
    const int gx  = x0 - HALO + r;
    const int gy0 = y0 - HALO + c2;
    const int gy1 = gy0 + 1;
    const int gxc  = min(max(gx, 0), NX - 1);
    const int gyc0 = min(max(gy0, 0), NY - 1);
    const int gyc1 = min(max(gy1, 0), NY - 1);
    const bool cUp = (gxc == 0), cDn = (gxc == NX - 1);
    const bool cL  = (gyc0 == 0), cR  = (gyc1 == NY - 1);
    const bool interior = (r >= HALO && r < HALO + TILE &&
                           c2 >= HALO && c2 < HALO + TILE);

    int sid0 = -1, sid1 = -1, pid0 = -1, pid1 = -1;
    for (int k = 0; k < N_SRC; ++k) {
        if (srcp[2*k] == gxc && srcp[2*k+1] == gyc0) sid0 = k;
        if (srcp[2*k] == gxc && srcp[2*k+1] == gyc1) sid1 = k;
    }
    if (interior)
        for (int k = 0; k < N_PROBE; ++k) {
            if (prbp[2*k] == gx && prbp[2*k+1] == gy0) pid0 = k;
            if (prbp[2*k] == gx && prbp[2*k+1] == gy1) pid1 = k;
        }

    // per-cell B in registers (f2 = {cell0, cell1})
    const f2 bX = { Bext[0*NX*NY + gxc*NY + gyc0], Bext[0*NX*NY + gxc*NY + gyc1] };
    const f2 bY = { Bext[1*NX*NY + gxc*NY + gyc0], Bext[1*NX*NY + gxc*NY + gyc1] };
    const f2 bZ = { Bext[2*NX*NY + gxc*NY + gyc0], Bext[2*NX*NY + gxc*NY + gyc1] };

    // relax (uniform -> exact pointwise identity)
    f2 m0, m1, m2;
    relax_ode2(bX, bY, bZ, dmg, m0, m1, m2);
    const f2 mrelz = m2;

    f2 a0 = 0.f, a1 = 0.f, a2 = 0.f;   // RK accumulators
    f2 f0, f1, f2v;                     // current-stage own values

    float* Fsig = F + (size_t)sg * 2 * FIELD;
    int* myflag = flags + blk * FLAG_STRIDE;

    for (int pr = 0; pr < NPAIR; ++pr) {
        // ---- handshake: poll 8 neighbors (relaxed), reload halo cells ----
        if (pr > 0) {
            if (tid < 8) {
                const int k = (tid < 4) ? tid : tid + 1;   // skip (0,0)
                const int nx = tbx + k / 3 - 1, ny = tby + k % 3 - 1;
                if (nx >= 0 && nx < NBX && ny >= 0 && ny < NBY) {
                    const int* fp = flags + (sg * BPS + nx * NBY + ny) * FLAG_STRIDE;
                    while (__hip_atomic_load(fp, __ATOMIC_RELAXED,
                                             __HIP_MEMORY_SCOPE_AGENT) < pr)
                        __builtin_amdgcn_s_sleep(1);
                }
            }
            __syncthreads();
            if (!interior) {
                const float* Fin = Fsig + (size_t)(pr & 1) * FIELD;
                const int g0 = gxc * NY + gyc0, g1 = gxc * NY + gyc1;
                m0.x = cohLoad(Fin + g0);            m0.y = cohLoad(Fin + g1);
                m1.x = cohLoad(Fin + NX*NY + g0);    m1.y = cohLoad(Fin + NX*NY + g1);
                m2.x = cohLoad(Fin + 2*NX*NY + g0);  m2.y = cohLoad(Fin + 2*NX*NY + g1);
            }
        }
        // stage m into bufA; f = m
        bufA[0][r][pp] = m0; bufA[1][r][pp] = m1; bufA[2][r][pp] = m2;
        f0 = m0; f1 = m1; f2v = m2;
        __syncthreads();

        for (int p = 0; p < 2; ++p) {
            const int tt = 2 * pr + p;
            f2 b2c = bZ;
            if (sid0 >= 0) b2c.x = bZ.x + sig[((size_t)sg*T_STEPS + tt)*N_SRC + sid0];
            if (sid1 >= 0) b2c.y = bZ.y + sig[((size_t)sg*T_STEPS + tt)*N_SRC + sid1];

            // accumulation/update region for this step (shrink 4p+4, edge-extended)
            const int rl  = atT ? HALO : 4*p + 4;
            const int rh  = atB ? HALO + TILE - 1 : 27 - 4*p;
            const int clo = atL ? HALO : 4*p + 4;
            const int chi = atR ? HALO + TILE - 1 : 27 - 4*p;
            const bool in0 = (r >= rl && r <= rh && c2   >= clo && c2   <= chi);
            const bool in1 = (r >= rl && r <= rh && c2+1 >= clo && c2+1 <= chi);

            for (int s = 1; s <= 4; ++s) {
                const int sh = 4*p + s;
                const int loi = atT ? HALO : sh;
                const int hiI = atB ? HALO + TILE - 1 : LDIM - 1 - sh;
                const int loj = atL ? HALO : sh;
                const int hiJ = atR ? HALO + TILE - 1 : LDIM - 1 - sh;
                const float cc = (s <= 2) ? H_HALF : H_STEP;
                const float w  = (s == 1 || s == 4) ? 1.0f : 2.0f;
                const f2 (*P)[LDIM][LPAIR] = (sh & 1) ? bufA : bufB;
                f2 (*Q)[LDIM][LPAIR] = (sh & 1) ? bufB : bufA;

                if (r >= loi && r <= hiI && c2 + 1 >= loj && c2 <= hiJ) {
                    const f2 fo[3] = { f0, f1, f2v };
                    f2 l[3];
                    #pragma unroll
                    for (int ch = 0; ch < 3; ++ch) {
                        const f2 up = cUp ? fo[ch] : P[ch][r-1][pp];
                        const f2 dn = cDn ? fo[ch] : P[ch][r+1][pp];
                        const float lf = cL ? fo[ch].x : P[ch][r][pp-1].y;
                        const float rt = cR ? fo[ch].y : P[ch][r][pp+1].x;
                        const f2 rgt = { fo[ch].y, rt };
                        const f2 lft = { lf, fo[ch].x };
                        // reference order: down + up + right + left - 4*m
                        l[ch] = dn + up + rgt + lft - 4.f * fo[ch];
                    }
                    f2 t0, t1, t2;
                    torque2(f0, f1, f2v,
                            bX + cex * l[0],
                            bY + cex * l[1],
                            b2c + cex * l[2] - dmg * f2v,
                            pref, alpha, t0, t1, t2);
                    // acc: guarded per cell (order ((k1+2k2)+2k3)+k4 preserved)
                    if (in0) { a0.x += w*t0.x; a1.x += w*t1.x; a2.x += w*t2.x; }
                    if (in1) { a0.y += w*t0.y; a1.y += w*t1.y; a2.y += w*t2.y; }
                    if (s < 4) {
                        f0 = m0 + cc*t0; f1 = m1 + cc*t1; f2v = m2 + cc*t2;
                        Q[0][r][pp] = f0; Q[1][r][pp] = f1; Q[2][r][pp] = f2v;
                    }
                }
                if (s < 4) __syncthreads();
            }

            // ---- step update (registers) ----
            if (in0) { m0.x += H_6*a0.x; m1.x += H_6*a1.x; m2.x += H_6*a2.x;
                       a0.x = 0.f; a1.x = 0.f; a2.x = 0.f; }
            if (in1) { m0.y += H_6*a0.y; m1.y += H_6*a1.y; m2.y += H_6*a2.y;
                       a0.y = 0.f; a1.y = 0.f; a2.y = 0.f; }
            f0 = m0; f1 = m1; f2v = m2;
            if (pid0 >= 0)
                out[((size_t)sg*T_STEPS + tt)*N_PROBE + pid0] = fb ? (m2.x - mrelz.x)*Msat : m2.x;
            if (pid1 >= 0)
                out[((size_t)sg*T_STEPS + tt)*N_PROBE + pid1] = fb ? (m2.y - mrelz.y)*Msat : m2.y;

            if (p == 0) {
                // re-stage updated m for the second half-step (sh=5 reads bufA)
                bufA[0][r][pp] = m0; bufA[1][r][pp] = m1; bufA[2][r][pp] = m2;
                __syncthreads();
            } else if (pr + 1 < NPAIR) {
                // ---- publish interior tile, drain, flag (all relaxed) ----
                if (interior) {
                    float* Fout = Fsig + (size_t)((pr + 1) & 1) * FIELD;
                    const int g0 = gx * NY + gy0;
                    cohStore(Fout + g0,               m0.x);
                    cohStore(Fout + g0 + 1,           m0.y);
                    cohStore(Fout + NX*NY + g0,       m1.x);
                    cohStore(Fout + NX*NY + g0 + 1,   m1.y);
                    cohStore(Fout + 2*NX*NY + g0,     m2.x);
                    cohStore(Fout + 2*NX*NY + g0 + 1, m2.y);
                }
                __builtin_amdgcn_s_waitcnt(0);   // own stores ack'd at coherence point
                __syncthreads();                  // whole block drained
                if (tid == 0)
                    __hip_atomic_store(myflag, pr + 1, __ATOMIC_RELAXED,
                                       __HIP_MEMORY_SCOPE_AGENT);
            }
        }
    }
}

extern "C" void kernel_launch(void* const* d_in, const int* in_sizes, int n_in,
                              void* d_out, int out_size, void* d_ws, size_t ws_size,
                              hipStream_t stream) {
    const float* sigp = (const float*)d_in[0];
    const float* Bext = (const float*)d_in[1];
    const float* Msat = (const float*)d_in[2];
    const int*   srcp = (const int*)d_in[3];
    const int*   prbp = (const int*)d_in[4];
    const int*   fbP  = (const int*)d_in[5];
    float* outp = (float*)d_out;
    float* F    = (float*)d_ws;                       // 3.15 MB
    int*   flags = (int*)((char*)d_ws + (size_t)F_TOTAL * sizeof(float)); // 32 KB

    init_flags<<<NBLOCKS * FLAG_STRIDE / 256, 256, 0, stream>>>(flags);

    void* args[] = { (void*)&sigp, (void*)&Bext, (void*)&Msat, (void*)&srcp,
                     (void*)&prbp, (void*)&fbP, (void*)&outp, (void*)&F,
                     (void*)&flags };
    hipLaunchCooperativeKernel((void*)mm_kernel, dim3(NBLOCKS), dim3(NTHR),
                               args, 0, stream);
}

// Round 8
// 1168.802 us; speedup vs baseline: 34.2162x; 1.0545x over previous
//
#include <hip/hip_runtime.h>

constexpr int NX = 256, NY = 256;
constexpr int T_STEPS = 256, N_SRC = 3, N_PROBE = 5;
constexpr int RELAX_STEPS = 100;
constexpr int TILE = 16, HALO = 8, LDIM = 32, LPAIR = 17; // 17 f2 = 34 floats pitch
constexpr int NBX = NX / TILE, NBY = NY / TILE;           // 16 x 16
constexpr int BPS = NBX * NBY;                            // 256 blocks/signal
constexpr int NSIG = 2;
constexpr int NBLOCKS = BPS * NSIG;                       // 512
constexpr int NTHR = 512;                                 // 1 thread : 2 j-adjacent cells
constexpr int NPAIR = T_STEPS / 2;                        // 128 exchanges
constexpr int FIELD = 3 * NX * NY;
constexpr int F_TOTAL = NSIG * 2 * FIELD;
constexpr int FLAG_STRIDE = 16;

constexpr float H_STEP = (float)(175950000000.0 * 5e-12);
constexpr float H_HALF = (float)(175950000000.0 * 5e-12 * 0.5);
constexpr float H_6    = (float)(175950000000.0 * 5e-12 / 6.0);
constexpr float CSOT   = 1e-4f;

typedef float f2 __attribute__((ext_vector_type(2)));
union F2U { f2 v; unsigned long long u; };

__global__ void init_flags(int* flags) {
    flags[blockIdx.x * blockDim.x + threadIdx.x] = 0;
}

// Packed (2-cell) LLG torque; per-lane trees token-identical to rounds 2-7.
__device__ __forceinline__ void torque2(f2 mx, f2 my, f2 mz,
                                        f2 B0, f2 B1, f2 B2,
                                        float pref, float alpha,
                                        f2& o0, f2& o1, f2& o2) {
    const f2 c10 = my * B2 - mz * B1;
    const f2 c11 = mz * B0 - mx * B2;
    const f2 c12 = mx * B1 - my * B0;
    const f2 c20 = my * c12 - mz * c11;
    const f2 c21 = mz * c10 - mx * c12;
    const f2 c22 = mx * c11 - my * c10;
    // sot = C_SOT * m x (m x (0,1,0)) = C_SOT*(mx*my, -(mx^2+mz^2), my*mz)
    o0 = pref * (c10 + alpha * c20) + CSOT * (my * mx);
    o1 = pref * (c11 + alpha * c21) - CSOT * (mx * mx + mz * mz);
    o2 = pref * (c12 + alpha * c22) + CSOT * (my * mz);
}

// relax: uniform field => Laplacian == 0.0f exactly; pointwise ODE, bit-identical
__device__ __forceinline__ void relax_ode2(f2 Bx, f2 By, f2 Bz, float dmg,
                                           f2& r0, f2& r1, f2& r2) {
    r0 = 0.0f; r1 = 1.0f; r2 = 0.0f;
    const float aR = 0.5f;
    const float pR = (float)(-(1.0 / (1.0 + 0.5 * 0.5)));
    for (int it = 0; it < RELAX_STEPS; ++it) {
        f2 k10,k11,k12,k20,k21,k22,k30,k31,k32,k40,k41,k42;
        torque2(r0,r1,r2, Bx,By,Bz - dmg*r2, pR,aR, k10,k11,k12);
        f2 u0=r0+H_HALF*k10, u1=r1+H_HALF*k11, u2=r2+H_HALF*k12;
        torque2(u0,u1,u2, Bx,By,Bz - dmg*u2, pR,aR, k20,k21,k22);
        u0=r0+H_HALF*k20; u1=r1+H_HALF*k21; u2=r2+H_HALF*k22;
        torque2(u0,u1,u2, Bx,By,Bz - dmg*u2, pR,aR, k30,k31,k32);
        u0=r0+H_STEP*k30; u1=r1+H_STEP*k31; u2=r2+H_STEP*k32;
        torque2(u0,u1,u2, Bx,By,Bz - dmg*u2, pR,aR, k40,k41,k42);
        r0 += H_6 * (((k10 + 2.0f*k20) + 2.0f*k30) + k40);
        r1 += H_6 * (((k11 + 2.0f*k21) + 2.0f*k31) + k41);
        r2 += H_6 * (((k12 + 2.0f*k22) + 2.0f*k32) + k42);
    }
}

// fine-grained device-coherent accessors (sc0 sc1; no cache-wide wbl2/inv)
__device__ __forceinline__ float cohLoad(const float* p) {
    return __hip_atomic_load(p, __ATOMIC_RELAXED, __HIP_MEMORY_SCOPE_AGENT);
}
__device__ __forceinline__ f2 cohLoad2(const float* p) {
    F2U x; x.u = __hip_atomic_load((const unsigned long long*)p,
                                   __ATOMIC_RELAXED, __HIP_MEMORY_SCOPE_AGENT);
    return x.v;
}
__device__ __forceinline__ void cohStore2(float* p, f2 v) {
    F2U x; x.v = v;
    __hip_atomic_store((unsigned long long*)p, x.u,
                       __ATOMIC_RELAXED, __HIP_MEMORY_SCOPE_AGENT);
}

__global__ __launch_bounds__(NTHR, 4)
void mm_kernel(const float* __restrict__ sig,    // [NSIG][T_STEPS][N_SRC]
               const float* __restrict__ Bext,   // [3][NX][NY]
               const float* __restrict__ MsatP,
               const int*   __restrict__ srcp,   // [N_SRC][2]
               const int*   __restrict__ prbp,   // [N_PROBE][2]
               const int*   __restrict__ fbP,
               float* __restrict__ out,          // [NSIG][T_STEPS][N_PROBE]
               float* __restrict__ F,            // ping-pong exchange buffers
               int*   __restrict__ flags)
{
    // 2 exchange buffers: 2 x 3 x 32 x 17 x 8B = 26.1 KB
    __shared__ f2 bufA[3][LDIM][LPAIR];
    __shared__ f2 bufB[3][LDIM][LPAIR];

    const int tid = threadIdx.x;
    const int blk = blockIdx.x;
    // signal-interleaved mapping: co-resident blocks on a CU likely belong to
    // different (independent) signals -> decorrelated handshake stalls
    const int sg = blk & 1;
    const int b  = blk >> 1;
    const int tbx = b / NBY, tby = b % NBY;
    const int x0 = tbx * TILE, y0 = tby * TILE;
    const bool atT = (tbx == 0), atB = (tbx == NBX - 1);
    const bool atL = (tby == 0), atR = (tby == NBY - 1);

    const float Msat = MsatP[0];
    const float cex = 7e-12f / (Msat * 5e-8f * 5e-8f);
    const float dmg = (float)(4e-7 * 3.14159265358979323846) * Msat;
    const int fb = fbP[0];
    const float alpha = 0.01f;
    const float pref  = (float)(-(1.0 / (1.0 + 0.01 * 0.01)));

    // fixed cell ownership: thread -> row r, pair pp (cols c2, c2+1)
    const int r  = tid >> 4;
    const int pp = tid & 15;
    const int c2 = pp << 1;
    const int gx  = x0 - HALO + r;
    const int gy0 = y0 - HALO + c2;
    const int gy1 = gy0 + 1;
    const int gxc  = min(max(gx, 0), NX - 1);
    const int gyc0 = min(max(gy0, 0), NY - 1);
    const int gyc1 = min(max(gy1, 0), NY - 1);
    const bool cUp = (gxc == 0), cDn = (gxc == NX - 1);
    const bool cL  = (gyc0 == 0), cR  = (gyc1 == NY - 1);
    const bool interior = (r >= HALO && r < HALO + TILE &&
                           c2 >= HALO && c2 < HALO + TILE);
    // contiguous 8B pair in global memory iff cols didn't collapse under clamping
    const bool pairOK = (gy0 >= 0 && gy0 <= NY - 2);
    // source tile of this thread's cells (valid for own tile too)
    const int srcFlagIdx = sg * BPS + (gxc >> 4) * NBY + (gyc0 >> 4);

    int sid0 = -1, sid1 = -1, pid0 = -1, pid1 = -1;
    for (int k = 0; k < N_SRC; ++k) {
        if (srcp[2*k] == gxc && srcp[2*k+1] == gyc0) sid0 = k;
        if (srcp[2*k] == gxc && srcp[2*k+1] == gyc1) sid1 = k;
    }
    if (interior)
        for (int k = 0; k < N_PROBE; ++k) {
            if (prbp[2*k] == gx && prbp[2*k+1] == gy0) pid0 = k;
            if (prbp[2*k] == gx && prbp[2*k+1] == gy1) pid1 = k;
        }

    // per-cell B in registers
    const f2 bX = { Bext[0*NX*NY + gxc*NY + gyc0], Bext[0*NX*NY + gxc*NY + gyc1] };
    const f2 bY = { Bext[1*NX*NY + gxc*NY + gyc0], Bext[1*NX*NY + gxc*NY + gyc1] };
    const f2 bZ = { Bext[2*NX*NY + gxc*NY + gyc0], Bext[2*NX*NY + gxc*NY + gyc1] };

    // relax (uniform -> exact pointwise identity)
    f2 m0, m1, m2;
    relax_ode2(bX, bY, bZ, dmg, m0, m1, m2);
    const f2 mrelz = m2;

    f2 a0 = 0.f, a1 = 0.f, a2 = 0.f;   // RK accumulators
    f2 f0, f1, f2v;                     // current-stage own values

    float* Fsig = F + (size_t)sg * 2 * FIELD;
    int* myflag = flags + (sg * BPS + b) * FLAG_STRIDE;

    // initial staging: full tile = relaxed m
    bufA[0][r][pp] = m0; bufA[1][r][pp] = m1; bufA[2][r][pp] = m2;
    f0 = m0; f1 = m1; f2v = m2;

    for (int pr = 0; pr < NPAIR; ++pr) {
        // ---- per-thread handshake: poll OWN source tile, reload, stage ----
        if (pr > 0 && !interior) {
            const int* fp = flags + srcFlagIdx * FLAG_STRIDE;
            while (__hip_atomic_load(fp, __ATOMIC_RELAXED,
                                     __HIP_MEMORY_SCOPE_AGENT) < pr)
                __builtin_amdgcn_s_sleep(1);
            const float* Fin = Fsig + (size_t)(pr & 1) * FIELD;
            if (pairOK) {
                const int g0 = gxc * NY + gy0;
                m0 = cohLoad2(Fin + g0);
                m1 = cohLoad2(Fin + NX*NY + g0);
                m2 = cohLoad2(Fin + 2*NX*NY + g0);
            } else {
                const int gg = gxc * NY + gyc0;      // collapsed duplicate cell
                const float v0 = cohLoad(Fin + gg);
                const float v1 = cohLoad(Fin + NX*NY + gg);
                const float v2 = cohLoad(Fin + 2*NX*NY + gg);
                m0 = f2{v0, v0}; m1 = f2{v1, v1}; m2 = f2{v2, v2};
            }
            bufA[0][r][pp] = m0; bufA[1][r][pp] = m1; bufA[2][r][pp] = m2;
            f0 = m0; f1 = m1; f2v = m2;
        }
        // sig prefetch for both half-steps (tiny; overlaps with barrier)
        f2 b2cs[2] = { bZ, bZ };
        if (sid0 >= 0) {
            b2cs[0].x = bZ.x + sig[((size_t)sg*T_STEPS + 2*pr    )*N_SRC + sid0];
            b2cs[1].x = bZ.x + sig[((size_t)sg*T_STEPS + 2*pr + 1)*N_SRC + sid0];
        }
        if (sid1 >= 0) {
            b2cs[0].y = bZ.y + sig[((size_t)sg*T_STEPS + 2*pr    )*N_SRC + sid1];
            b2cs[1].y = bZ.y + sig[((size_t)sg*T_STEPS + 2*pr + 1)*N_SRC + sid1];
        }
        __syncthreads();

        for (int p = 0; p < 2; ++p) {
            const f2 b2c = b2cs[p];

            for (int s = 1; s <= 4; ++s) {
                const int sh = 4*p + s;
                const int loi = atT ? HALO : sh;
                const int hiI = atB ? HALO + TILE - 1 : LDIM - 1 - sh;
                const int loj = atL ? HALO : sh;
                const int hiJ = atR ? HALO + TILE - 1 : LDIM - 1 - sh;
                const float cc = (s <= 2) ? H_HALF : H_STEP;
                const float w  = (s == 1 || s == 4) ? 1.0f : 2.0f;
                const f2 (*P)[LDIM][LPAIR] = (sh & 1) ? bufA : bufB;
                f2 (*Q)[LDIM][LPAIR] = (sh & 1) ? bufB : bufA;

                const bool active = (r >= loi && r <= hiI &&
                                     c2 + 1 >= loj && c2 <= hiJ);
                if (active) {
                    const f2 fo[3] = { f0, f1, f2v };
                    f2 l[3];
                    #pragma unroll
                    for (int ch = 0; ch < 3; ++ch) {
                        const f2 up = cUp ? fo[ch] : P[ch][r-1][pp];
                        const f2 dn = cDn ? fo[ch] : P[ch][r+1][pp];
                        // j-neighbors via cross-lane (register == latest stage
                        // value of that lane; rects shrink monotonically so any
                        // needed lane was active at the previous stage)
                        const float lfs = __shfl_up(fo[ch].y, 1);
                        const float rts = __shfl_down(fo[ch].x, 1);
                        const float lf = cL ? fo[ch].x : lfs;
                        const float rt = cR ? fo[ch].y : rts;
                        const f2 rgt = { fo[ch].y, rt };
                        const f2 lft = { lf, fo[ch].x };
                        // reference order: down + up + right + left - 4*m
                        l[ch] = dn + up + rgt + lft - 4.f * fo[ch];
                    }
                    f2 t0, t1, t2;
                    torque2(f0, f1, f2v,
                            bX + cex * l[0],
                            bY + cex * l[1],
                            b2c + cex * l[2] - dmg * f2v,
                            pref, alpha, t0, t1, t2);
                    if (s < 4) {
                        // acc region (shrink 4p+4) is a strict subset: guard
                        const bool inr = (r >= (atT ? HALO : 4*p + 4) &&
                                          r <= (atB ? HALO+TILE-1 : 27 - 4*p) &&
                                          c2 >= (atL ? HALO : 4*p + 4) &&
                                          c2 <= (atR ? HALO+TILE-1 : 27 - 4*p));
                        if (inr) { a0 += w*t0; a1 += w*t1; a2 += w*t2; }
                        f0 = m0 + cc*t0; f1 = m1 + cc*t1; f2v = m2 + cc*t2;
                        Q[0][r][pp] = f0; Q[1][r][pp] = f1; Q[2][r][pp] = f2v;
                    } else {
                        // s==4: active set == update region exactly (parity) ->
                        // merged epilogue: ((k1+2k2)+2k3)+k4 order preserved
                        a0 += w*t0; a1 += w*t1; a2 += w*t2;
                        m0 += H_6*a0; m1 += H_6*a1; m2 += H_6*a2;
                        a0 = 0.f; a1 = 0.f; a2 = 0.f;
                        f0 = m0; f1 = m1; f2v = m2;
                        Q[0][r][pp] = m0; Q[1][r][pp] = m1; Q[2][r][pp] = m2;
                        const int tt = 2*pr + p;
                        if (pid0 >= 0)
                            out[((size_t)sg*T_STEPS + tt)*N_PROBE + pid0] =
                                fb ? (m2.x - mrelz.x)*Msat : m2.x;
                        if (pid1 >= 0)
                            out[((size_t)sg*T_STEPS + tt)*N_PROBE + pid1] =
                                fb ? (m2.y - mrelz.y)*Msat : m2.y;
                        if (p == 1 && pr + 1 < NPAIR && interior) {
                            float* Fout = Fsig + (size_t)((pr + 1) & 1) * FIELD;
                            const int g0 = gx * NY + gy0;
                            cohStore2(Fout + g0,          m0);
                            cohStore2(Fout + NX*NY + g0,  m1);
                            cohStore2(Fout + 2*NX*NY + g0, m2);
                        }
                    }
                }
                // drain own publish stores before the barrier so the flag
                // release (tid 0, after barrier) implies data at LLC
                if (p == 1 && s == 4 && pr + 1 < NPAIR)
                    __builtin_amdgcn_s_waitcnt(0);
                __syncthreads();
            }
        }
        if (pr + 1 < NPAIR && tid == 0)
            __hip_atomic_store(myflag, pr + 1, __ATOMIC_RELAXED,
                               __HIP_MEMORY_SCOPE_AGENT);
    }
}

extern "C" void kernel_launch(void* const* d_in, const int* in_sizes, int n_in,
                              void* d_out, int out_size, void* d_ws, size_t ws_size,
                              hipStream_t stream) {
    const float* sigp = (const float*)d_in[0];
    const float* Bext = (const float*)d_in[1];
    const float* Msat = (const float*)d_in[2];
    const int*   srcp = (const int*)d_in[3];
    const int*   prbp = (const int*)d_in[4];
    const int*   fbP  = (const int*)d_in[5];
    float* outp = (float*)d_out;
    float* F    = (float*)d_ws;                       // 3.15 MB
    int*   flags = (int*)((char*)d_ws + (size_t)F_TOTAL * sizeof(float)); // 32 KB

    init_flags<<<NBLOCKS * FLAG_STRIDE / 256, 256, 0, stream>>>(flags);

    void* args[] = { (void*)&sigp, (void*)&Bext, (void*)&Msat, (void*)&srcp,
                     (void*)&prbp, (void*)&fbP, (void*)&outp, (void*)&F,
                     (void*)&flags };
    hipLaunchCooperativeKernel((void*)mm_kernel, dim3(NBLOCKS), dim3(NTHR),
                               args, 0, stream);
}